// Round 1
// baseline (2508.528 us; speedup 1.0000x reference)
//
#include <hip/hip_runtime.h>
#include <hip/hip_cooperative_groups.h>
#include <math.h>

namespace cg = cooperative_groups;

// B=64, T=32, D=768, NH=2, dk=384, N=901 (1 cls + 900 local)

typedef short bf16x8 __attribute__((ext_vector_type(8)));
typedef float f32x4 __attribute__((ext_vector_type(4)));
typedef unsigned short ushort_t;

__device__ __forceinline__ unsigned short f2b(float f) {
    unsigned int u = __float_as_uint(f);
    unsigned int r = (u + 0x7FFFu + ((u >> 16) & 1u)) >> 16;
    return (unsigned short)r;
}
__device__ __forceinline__ float b2f(unsigned short s) {
    return __uint_as_float(((unsigned int)s) << 16);
}
__device__ __forceinline__ float sigm(float x) { return 1.f / (1.f + __expf(-x)); }
__device__ __forceinline__ float tanhx(float x) {
    x = fminf(fmaxf(x, -15.f), 15.f);
    float e = __expf(2.f * x);
    return (e - 1.f) / (e + 1.f);
}

// ---------------- tiny helpers ----------------

__global__ void k_pool_sums(const float* gp, const float* lp, float* out) {
    int t = threadIdx.x;
    float v1 = (t < 32) ? gp[t] : 0.f;
    float v2 = (t < 32) ? lp[t] : 0.f;
#pragma unroll
    for (int m = 1; m < 32; m <<= 1) { v1 += __shfl_xor(v1, m, 64); v2 += __shfl_xor(v2, m, 64); }
    if (t == 0) { out[0] = v1; out[1] = v2; }
}

__global__ void k_cvt(const float* __restrict__ src, ushort_t* __restrict__ dst,
                      float* __restrict__ dst32, int n) {
    int i = blockIdx.x * 256 + threadIdx.x;
    if (i < n) {
        float v = src[i];
        dst[i] = f2b(v);
        if (dst32) dst32[i] = v;
    }
}

// C[m][n] = s1 * (A@B)[m][n] + s2 * bias[n], M==64 fixed (4 rows/block), optional relu / transB.
__global__ void __launch_bounds__(256) k_sgemm(
    const float* __restrict__ A, long lda,
    const float* __restrict__ B, int ldb, int transB,
    const float* __restrict__ bias, const float* s1p, const float* s2p,
    float* __restrict__ C, int ldc, int N, int K, int relu)
{
    __shared__ float As[4 * 1536];
    int m0 = blockIdx.y * 4;
    int n = blockIdx.x * 256 + threadIdx.x;
    for (int r = 0; r < 4; r++)
        for (int k = threadIdx.x; k < K; k += 256)
            As[r * K + k] = A[(long)(m0 + r) * lda + k];
    __syncthreads();
    if (n >= N) return;
    float a0 = 0, a1 = 0, a2 = 0, a3 = 0;
    if (!transB) {
        for (int k = 0; k < K; k++) {
            float bv = B[(long)k * ldb + n];
            a0 += As[k] * bv; a1 += As[K + k] * bv; a2 += As[2 * K + k] * bv; a3 += As[3 * K + k] * bv;
        }
    } else {
        const float* Bp = B + (long)n * ldb;
        for (int k = 0; k < K; k += 4) {
            float4 bv = *(const float4*)(Bp + k);
            a0 += As[k] * bv.x + As[k + 1] * bv.y + As[k + 2] * bv.z + As[k + 3] * bv.w;
            a1 += As[K + k] * bv.x + As[K + k + 1] * bv.y + As[K + k + 2] * bv.z + As[K + k + 3] * bv.w;
            a2 += As[2 * K + k] * bv.x + As[2 * K + k + 1] * bv.y + As[2 * K + k + 2] * bv.z + As[2 * K + k + 3] * bv.w;
            a3 += As[3 * K + k] * bv.x + As[3 * K + k + 1] * bv.y + As[3 * K + k + 2] * bv.z + As[3 * K + k + 3] * bv.w;
        }
    }
    float s1 = s1p ? *s1p : 1.f;
    float s2 = s2p ? *s2p : 1.f;
    float bv = bias ? bias[n] * s2 : 0.f;
    float o0 = a0 * s1 + bv, o1 = a1 * s1 + bv, o2 = a2 * s1 + bv, o3 = a3 * s1 + bv;
    if (relu) { o0 = fmaxf(o0, 0.f); o1 = fmaxf(o1, 0.f); o2 = fmaxf(o2, 0.f); o3 = fmaxf(o3, 0.f); }
    C[(long)(m0 + 0) * ldc + n] = o0;
    C[(long)(m0 + 1) * ldc + n] = o1;
    C[(long)(m0 + 2) * ldc + n] = o2;
    C[(long)(m0 + 3) * ldc + n] = o3;
}

// base[b][j] = wx[b][j] + b_ih[j] (+ b_hh[j] for r,z gates)
__global__ void k_base(const float* __restrict__ wx, const float* __restrict__ bih,
                       const float* __restrict__ bhh, float* __restrict__ base) {
    int i = blockIdx.x * 256 + threadIdx.x;
    if (i < 64 * 2304) {
        int j = i % 2304;
        float v = wx[i] + bih[j];
        if (j < 1536) v += bhh[j];
        base[i] = v;
    }
}

// ---------------- GRU scan ----------------
// 12 blocks x 256. Block owns 64 d-columns (wave owns 16). Wave computes the three
// gate columns {d, 768+d, 1536+d} for all 64 batch rows via MFMA, then the GRU
// pointwise update fully in-register (gate-aligned n-tiles). 1 grid sync / step.

__device__ __forceinline__ void gru_step(
    int t, const ushort_t* __restrict__ h0b, const ushort_t* __restrict__ whh,
    const float* __restrict__ base, float bhhn,
    float* __restrict__ h, ushort_t* __restrict__ qemb,
    int d0, int quad, int l16)
{
    const ushort_t* Ap = (t == 0) ? h0b : (qemb + (long)(t - 1) * 768);
    long ldA = (t == 0) ? 768 : 32 * 768;
    int d = d0 + l16;
    f32x4 zz4 = {0.f, 0.f, 0.f, 0.f};
    f32x4 acc[3][4];
#pragma unroll
    for (int g = 0; g < 3; g++)
#pragma unroll
        for (int mi = 0; mi < 4; mi++) acc[g][mi] = zz4;
    for (int kk = 0; kk < 768; kk += 32) {
        bf16x8 af[4];
#pragma unroll
        for (int mi = 0; mi < 4; mi++)
            af[mi] = *(const bf16x8*)(Ap + (long)(mi * 16 + l16) * ldA + kk + quad * 8);
#pragma unroll
        for (int g = 0; g < 3; g++) {
            bf16x8 bfr = *(const bf16x8*)(whh + (long)(g * 768 + d0 + l16) * 768 + kk + quad * 8);
#pragma unroll
            for (int mi = 0; mi < 4; mi++)
                acc[g][mi] = __builtin_amdgcn_mfma_f32_16x16x32_bf16(af[mi], bfr, acc[g][mi], 0, 0, 0);
        }
    }
#pragma unroll
    for (int mi = 0; mi < 4; mi++) {
#pragma unroll
        for (int r = 0; r < 4; r++) {
            int b = mi * 16 + quad * 4 + r;
            const float* bb = base + b * 2304;
            float rr = sigm(acc[0][mi][r] + bb[d]);
            float zg = sigm(acc[1][mi][r] + bb[768 + d]);
            float nn = tanhx(bb[1536 + d] + rr * (acc[2][mi][r] + bhhn));
            float hv = h[b * 768 + d];
            float hnew = (1.f - zg) * nn + zg * hv;
            h[b * 768 + d] = hnew;
            qemb[(long)(b * 32 + t) * 768 + d] = f2b(hnew);
        }
    }
}

__global__ void __launch_bounds__(256) k_gru_coop(
    const ushort_t* h0b, const ushort_t* whh, const float* base,
    const float* bhh, float* h, ushort_t* qemb)
{
    cg::grid_group grid = cg::this_grid();
    int wv = threadIdx.x >> 6, lane = threadIdx.x & 63;
    int quad = lane >> 4, l16 = lane & 15;
    int d0 = blockIdx.x * 64 + wv * 16;
    float bhhn = bhh[1536 + d0 + l16];
    for (int t = 0; t < 32; t++) {
        gru_step(t, h0b, whh, base, bhhn, h, qemb, d0, quad, l16);
        grid.sync();
    }
}

__global__ void __launch_bounds__(256) k_gru_step(
    int t, const ushort_t* h0b, const ushort_t* whh, const float* base,
    const float* bhh, float* h, ushort_t* qemb)
{
    int wv = threadIdx.x >> 6, lane = threadIdx.x & 63;
    int quad = lane >> 4, l16 = lane & 15;
    int d0 = blockIdx.x * 64 + wv * 16;
    float bhhn = bhh[1536 + d0 + l16];
    gru_step(t, h0b, whh, base, bhhn, h, qemb, d0, quad, l16);
}

// ---------------- generic bf16 MFMA GEMM (64x64 tile) ----------------
// C(bf16)[orow][n] = A[M,K]bf16 @ B + bias. transB: B stored [N][K] row-major.
// remap!=0: orow = (row/32)*64 + rowoff + row%32  (head interleave for Qt).
__global__ void __launch_bounds__(256) k_gemm_bf16(
    const ushort_t* __restrict__ A, int lda,
    const ushort_t* __restrict__ B, int ldb, int transB,
    const float* __restrict__ bias,
    ushort_t* __restrict__ Cb, int ldc,
    int K, int remap, int rowoff)
{
    __shared__ __align__(16) ushort_t As[64][72];
    __shared__ __align__(16) ushort_t Bs[64][72];
    int tid = threadIdx.x;
    int wv = tid >> 6, lane = tid & 63, quad = lane >> 4, l16 = lane & 15;
    long bm = (long)blockIdx.y * 64, bn = (long)blockIdx.x * 64;
    f32x4 zz4 = {0.f, 0.f, 0.f, 0.f};
    f32x4 acc[4];
#pragma unroll
    for (int mi = 0; mi < 4; mi++) acc[mi] = zz4;
    int row4 = tid >> 2, seg = tid & 3;
    for (int k0 = 0; k0 < K; k0 += 64) {
        {
            const ushort_t* src = A + (bm + row4) * lda + k0 + seg * 16;
            *(bf16x8*)&As[row4][seg * 16] = *(const bf16x8*)src;
            *(bf16x8*)&As[row4][seg * 16 + 8] = *(const bf16x8*)(src + 8);
        }
        if (transB) {
            const ushort_t* src = B + (bn + row4) * ldb + k0 + seg * 16;
            *(bf16x8*)&Bs[row4][seg * 16] = *(const bf16x8*)src;
            *(bf16x8*)&Bs[row4][seg * 16 + 8] = *(const bf16x8*)(src + 8);
        } else {
            const ushort_t* src = B + (long)(k0 + row4) * ldb + bn + seg * 16;
            bf16x8 v0 = *(const bf16x8*)src;
            bf16x8 v1 = *(const bf16x8*)(src + 8);
#pragma unroll
            for (int i = 0; i < 8; i++) {
                Bs[seg * 16 + i][row4] = (ushort_t)v0[i];
                Bs[seg * 16 + 8 + i][row4] = (ushort_t)v1[i];
            }
        }
        __syncthreads();
#pragma unroll
        for (int ks = 0; ks < 64; ks += 32) {
            bf16x8 bfr = *(const bf16x8*)&Bs[wv * 16 + l16][ks + quad * 8];
#pragma unroll
            for (int mi = 0; mi < 4; mi++) {
                bf16x8 af = *(const bf16x8*)&As[mi * 16 + l16][ks + quad * 8];
                acc[mi] = __builtin_amdgcn_mfma_f32_16x16x32_bf16(af, bfr, acc[mi], 0, 0, 0);
            }
        }
        __syncthreads();
    }
    int ncol = (int)bn + wv * 16 + l16;
    float bv = bias ? bias[ncol] : 0.f;
#pragma unroll
    for (int mi = 0; mi < 4; mi++) {
#pragma unroll
        for (int r = 0; r < 4; r++) {
            long row = bm + mi * 16 + quad * 4 + r;
            long orow = remap ? ((row >> 5) * 64 + rowoff + (row & 31)) : row;
            Cb[orow * ldc + ncol] = f2b(acc[mi][r] + bv);
        }
    }
}

// qb[b*64 + h*32 + q] = Q_h[b,q,:] . la_b1_h
__global__ void k_qb(const ushort_t* __restrict__ Qb, const float* __restrict__ lb1,
                     float* __restrict__ qbv) {
    int i = blockIdx.x * 256 + threadIdx.x;
    if (i >= 4096) return;
    int b = i >> 6, r = i & 63, hh = r >> 5, q = r & 31;
    const ushort_t* src = Qb + (long)(b * 32 + q) * 768 + hh * 384;
    const float* bb = lb1 + hh * 384;
    float s = 0.f;
    for (int k = 0; k < 384; k++) s += b2f(src[k]) * bb[k];
    qbv[i] = s;
}

// ---------------- fused flash attention over img_loc (the heavy kernel) ----------------
// One block per b. 64 rows = 2 heads x 32 queries. Online softmax over 900 keys in
// 29 tiles of 32. S = Qt @ x^T via MFMA; ctxX += P @ x via MFMA (acc 96 VGPR/lane).
__global__ void __launch_bounds__(512) k_flash(
    const float* __restrict__ img, const ushort_t* __restrict__ Qt,
    const float* __restrict__ qb, float* __restrict__ ctxX)
{
    __shared__ __align__(16) ushort_t xs[32][776];
    __shared__ float Sls[64][36];
    __shared__ __align__(16) ushort_t Pls[64][40];
    __shared__ float m_s[64], l_s[64], al_s[64], qb_s[64];
    int b = blockIdx.x;
    int tid = threadIdx.x;
    int wv = tid >> 6, lane = tid & 63, quad = lane >> 4, l16 = lane & 15;
    if (tid < 64) { qb_s[tid] = qb[b * 64 + tid]; m_s[tid] = -1e30f; l_s[tid] = 0.f; }
    f32x4 zz4 = {0.f, 0.f, 0.f, 0.f};
    f32x4 acc[4][6];
#pragma unroll
    for (int mi = 0; mi < 4; mi++)
#pragma unroll
        for (int nj = 0; nj < 6; nj++) acc[mi][nj] = zz4;
    const float rs = 0.051031036307982884f; // 1/sqrt(384)
    int smi = wv & 3, sni = wv >> 2;
    __syncthreads();
    for (int t0 = 0; t0 < 29; t0++) {
        int key0 = t0 * 32;
        { // stage x tile (fp32 global -> bf16 LDS), zero-fill past key 899
            int keyl = tid >> 4, dseg = tid & 15;
            int key = key0 + keyl;
            const float* src = img + ((long)b * 901 + 1 + key) * 768;
            bool ok = key < 900;
#pragma unroll
            for (int c = 0; c < 12; c++) {
                int dd = c * 64 + dseg * 4;
                float x0 = 0, x1 = 0, x2 = 0, x3 = 0;
                if (ok) { float4 v = *(const float4*)(src + dd); x0 = v.x; x1 = v.y; x2 = v.z; x3 = v.w; }
                ushort_t* dst = &xs[keyl][dd];
                dst[0] = f2b(x0); dst[1] = f2b(x1); dst[2] = f2b(x2); dst[3] = f2b(x3);
            }
        }
        __syncthreads();
        { // S = Qt @ x^T  (wave -> one 16x16 tile of [64 x 32])
            f32x4 as = zz4;
            const ushort_t* qrow = Qt + (long)(b * 64 + smi * 16 + l16) * 768 + quad * 8;
            const ushort_t* xrow = &xs[sni * 16 + l16][quad * 8];
#pragma unroll
            for (int kk = 0; kk < 768; kk += 32) {
                bf16x8 aq = *(const bf16x8*)(qrow + kk);
                bf16x8 bx = *(const bf16x8*)(xrow + kk);
                as = __builtin_amdgcn_mfma_f32_16x16x32_bf16(aq, bx, as, 0, 0, 0);
            }
#pragma unroll
            for (int r = 0; r < 4; r++) {
                int row = smi * 16 + quad * 4 + r;
                Sls[row][sni * 16 + l16] = (as[r] + qb_s[row]) * rs;
            }
        }
        __syncthreads();
        { // online softmax: 8 threads per row
            int row = tid >> 3, sub = tid & 7;
            float sv[4];
            float mx = -1e30f;
#pragma unroll
            for (int i = 0; i < 4; i++) {
                int kl = sub + i * 8;
                float s = (key0 + kl < 900) ? Sls[row][kl] : -1e30f;
                sv[i] = s; mx = fmaxf(mx, s);
            }
            mx = fmaxf(mx, __shfl_xor(mx, 1, 64));
            mx = fmaxf(mx, __shfl_xor(mx, 2, 64));
            mx = fmaxf(mx, __shfl_xor(mx, 4, 64));
            float mold = m_s[row];
            float mnew = fmaxf(mold, mx);
            float ss = 0.f;
#pragma unroll
            for (int i = 0; i < 4; i++) {
                float p = __expf(sv[i] - mnew);
                ss += p;
                Pls[row][sub + i * 8] = f2b(p);
            }
            ss += __shfl_xor(ss, 1, 64);
            ss += __shfl_xor(ss, 2, 64);
            ss += __shfl_xor(ss, 4, 64);
            if (sub == 0) {
                float alpha = __expf(mold - mnew);
                al_s[row] = alpha;
                l_s[row] = l_s[row] * alpha + ss;
                m_s[row] = mnew;
            }
        }
        __syncthreads();
        { // rescale + ctxX += P @ x   (wave owns 96 d-columns)
            bf16x8 pf[4];
#pragma unroll
            for (int mi = 0; mi < 4; mi++)
                pf[mi] = *(const bf16x8*)&Pls[mi * 16 + l16][quad * 8];
#pragma unroll
            for (int mi = 0; mi < 4; mi++) {
#pragma unroll
                for (int r = 0; r < 4; r++) {
                    float a = al_s[mi * 16 + quad * 4 + r];
#pragma unroll
                    for (int nj = 0; nj < 6; nj++) acc[mi][nj][r] *= a;
                }
            }
#pragma unroll
            for (int nj = 0; nj < 6; nj++) {
                int dd = wv * 96 + nj * 16 + l16;
                bf16x8 bx;
#pragma unroll
                for (int j = 0; j < 8; j++) bx[j] = (short)xs[quad * 8 + j][dd];
#pragma unroll
                for (int mi = 0; mi < 4; mi++)
                    acc[mi][nj] = __builtin_amdgcn_mfma_f32_16x16x32_bf16(pf[mi], bx, acc[mi][nj], 0, 0, 0);
            }
        }
        __syncthreads();
    }
#pragma unroll
    for (int mi = 0; mi < 4; mi++) {
#pragma unroll
        for (int r = 0; r < 4; r++) {
            int row = mi * 16 + quad * 4 + r;
            float inv = 1.f / l_s[row];
            float* dst = ctxX + ((long)b * 64 + row) * 768;
#pragma unroll
            for (int nj = 0; nj < 6; nj++)
                dst[wv * 96 + nj * 16 + l16] = acc[mi][nj][r] * inv;
        }
    }
}

// pooledX[b][h][d] = sum_q la_pool[q] * ctxX[b][h*32+q][d]
__global__ void k_poolctx(const float* __restrict__ ctxX, const float* __restrict__ lp,
                          float* __restrict__ plX) {
    int i = blockIdx.x * 256 + threadIdx.x;
    if (i >= 64 * 1536) return;
    int d = i % 768;
    int t = i / 768;
    int hh = t & 1, b = t >> 1;
    const float* src = ctxX + ((long)b * 64 + hh * 32) * 768 + d;
    float s = 0.f;
    for (int q = 0; q < 32; q++) s += lp[q] * src[(long)q * 768];
    plX[i] = s;
}

// ---------------- host launcher ----------------

extern "C" void kernel_launch(void* const* d_in, const int* in_sizes, int n_in,
                              void* d_out, int out_size, void* d_ws, size_t ws_size,
                              hipStream_t stream)
{
    const float* img  = (const float*)d_in[1];
    const float* h0   = (const float*)d_in[2];
    const float* w_ih = (const float*)d_in[3];
    const float* w_hh = (const float*)d_in[4];
    const float* b_ih = (const float*)d_in[5];
    const float* b_hh = (const float*)d_in[6];
    const float* ga_w = (const float*)d_in[7];
    const float* ga_b = (const float*)d_in[8];
    const float* ga_pool = (const float*)d_in[9];
    const float* la_w = (const float*)d_in[10];
    const float* la_b = (const float*)d_in[11];
    const float* la_pool = (const float*)d_in[12];
    const float* go_w = (const float*)d_in[13];
    const float* go_b = (const float*)d_in[14];
    const float* go_pool = (const float*)d_in[15];
    const float* f1w = (const float*)d_in[16];
    const float* f1b = (const float*)d_in[17];
    const float* f2w = (const float*)d_in[18];
    const float* f2b_ = (const float*)d_in[19];
    const float* f3w = (const float*)d_in[20];
    const float* f3b = (const float*)d_in[21];
    float* out = (float*)d_out;
    (void)in_sizes; (void)n_in; (void)out_size; (void)ws_size;

    char* w = (char*)d_ws;
    auto alloc = [&](size_t bytes) -> char* {
        char* p = w; w += (bytes + 255) & ~(size_t)255; return p;
    };
    float*    scal  = (float*)alloc(256);                 // [0]=S_go [1]=S_la
    ushort_t* whhb  = (ushort_t*)alloc((size_t)2304 * 768 * 2);
    ushort_t* law0b = (ushort_t*)alloc((size_t)768 * 768 * 2);
    ushort_t* law1b = (ushort_t*)alloc((size_t)768 * 768 * 2);
    ushort_t* h0b   = (ushort_t*)alloc((size_t)64 * 768 * 2);
    float*    hbuf  = (float*)alloc((size_t)64 * 768 * 4);
    float*    t12   = (float*)alloc((size_t)64 * 768 * 4);
    float*    avec  = (float*)alloc((size_t)64 * 768 * 4);
    float*    wx    = (float*)alloc((size_t)64 * 2304 * 4);
    float*    base  = (float*)alloc((size_t)64 * 2304 * 4);
    ushort_t* qembb = (ushort_t*)alloc((size_t)2048 * 768 * 2);
    ushort_t* Qb    = (ushort_t*)alloc((size_t)2048 * 768 * 2);
    ushort_t* Qtb   = (ushort_t*)alloc((size_t)4096 * 768 * 2);
    float*    qbv   = (float*)alloc((size_t)4096 * 4);
    float*    ctxX  = (float*)alloc((size_t)4096 * 768 * 4);
    float*    plX   = (float*)alloc((size_t)64 * 1536 * 4);
    float*    pc    = (float*)alloc((size_t)64 * 768 * 4);
    float*    hcat  = (float*)alloc((size_t)64 * 1536 * 4);
    float*    x1    = (float*)alloc((size_t)64 * 1024 * 4);
    float*    x2    = (float*)alloc((size_t)64 * 512 * 4);

    const float* ga_w2 = ga_w + 2 * 768 * 768; const float* ga_w3 = ga_w + 3 * 768 * 768;
    const float* ga_b2 = ga_b + 2 * 768;       const float* ga_b3 = ga_b + 3 * 768;
    const float* go_w2 = go_w + 2 * 768 * 768; const float* go_w3 = go_w + 3 * 768 * 768;
    const float* go_b2 = go_b + 2 * 768;       const float* go_b3 = go_b + 3 * 768;
    const float* la_w0 = la_w;                 const float* la_w1 = la_w + 768 * 768;
    const float* la_w2 = la_w + 2 * 768 * 768; const float* la_w3 = la_w + 3 * 768 * 768;
    const float* la_b0 = la_b;                 const float* la_b1 = la_b + 768;
    const float* la_b2 = la_b + 2 * 768;       const float* la_b3 = la_b + 3 * 768;

    dim3 blk(256);
    k_pool_sums<<<1, 64, 0, stream>>>(go_pool, la_pool, scal);
    k_cvt<<<6912, blk, 0, stream>>>(w_hh, whhb, nullptr, 2304 * 768);
    k_cvt<<<2304, blk, 0, stream>>>(la_w0, law0b, nullptr, 768 * 768);
    k_cvt<<<2304, blk, 0, stream>>>(la_w1, law1b, nullptr, 768 * 768);
    k_cvt<<<192, blk, 0, stream>>>(h0, h0b, hbuf, 64 * 768);

    // ga path (constant GRU input) + go path (softmax over 1 key collapses both)
    k_sgemm<<<dim3(3, 16), blk, 0, stream>>>(img, (long)901 * 768, ga_w2, 768, 0, ga_b2, nullptr, nullptr, t12, 768, 768, 768, 0);
    k_sgemm<<<dim3(3, 16), blk, 0, stream>>>(t12, 768, ga_w3, 768, 0, ga_b3, ga_pool, ga_pool, avec, 768, 768, 768, 0);
    k_sgemm<<<dim3(9, 16), blk, 0, stream>>>(avec, 768, w_ih, 768, 1, nullptr, nullptr, nullptr, wx, 2304, 2304, 768, 0);
    k_base<<<576, blk, 0, stream>>>(wx, b_ih, b_hh, base);
    k_sgemm<<<dim3(3, 16), blk, 0, stream>>>(img, (long)901 * 768, go_w2, 768, 0, go_b2, nullptr, nullptr, t12, 768, 768, 768, 0);
    k_sgemm<<<dim3(3, 16), blk, 0, stream>>>(t12, 768, go_w3, 768, 0, go_b3, scal, scal, hcat + 768, 1536, 768, 768, 0);

    // GRU scan (cooperative; fallback to 32 step launches if coop launch refused)
    {
        const ushort_t* a0 = h0b; const ushort_t* a1 = whhb; const float* a2 = base;
        const float* a3 = b_hh; float* a4 = hbuf; ushort_t* a5 = qembb;
        void* args[6] = { &a0, &a1, &a2, &a3, &a4, &a5 };
        hipError_t e = hipLaunchCooperativeKernel((void*)k_gru_coop, dim3(12), dim3(256),
                                                  args, 0, stream);
        if (e != hipSuccess) {
            for (int t = 0; t < 32; t++)
                k_gru_step<<<12, blk, 0, stream>>>(t, h0b, whhb, base, b_hh, hbuf, qembb);
        }
    }

    // Q = q_emb @ la_w0 + la_b0 ; Qt_h = Q_h @ W1_h^T (folded-K trick) ; qb = Q_h . b1_h
    k_gemm_bf16<<<dim3(12, 32), blk, 0, stream>>>(qembb, 768, law0b, 768, 0, la_b0, Qb, 768, 768, 0, 0);
    k_gemm_bf16<<<dim3(12, 32), blk, 0, stream>>>(Qb, 768, law1b, 768, 1, nullptr, Qtb, 768, 384, 1, 0);
    k_gemm_bf16<<<dim3(12, 32), blk, 0, stream>>>(Qb + 384, 768, law1b + 384, 768, 1, nullptr, Qtb, 768, 384, 1, 32);
    k_qb<<<16, blk, 0, stream>>>(Qb, la_b1, qbv);

    k_flash<<<64, dim3(512), 0, stream>>>(img, Qtb, qbv, ctxX);

    // pool over q, then project: pc = pooledX @ W2_h + S_la*b2_h ; local_out = pc @ w3 + S_la*b3
    k_poolctx<<<384, blk, 0, stream>>>(ctxX, la_pool, plX);
    k_sgemm<<<dim3(2, 16), blk, 0, stream>>>(plX, 1536, la_w2, 768, 0, la_b2, nullptr, scal + 1, pc, 768, 384, 768, 0);
    k_sgemm<<<dim3(2, 16), blk, 0, stream>>>(plX + 768, 1536, la_w2 + 384, 768, 0, la_b2 + 384, nullptr, scal + 1, pc + 384, 768, 384, 768, 0);
    k_sgemm<<<dim3(3, 16), blk, 0, stream>>>(pc, 768, la_w3, 768, 0, la_b3, nullptr, scal + 1, hcat, 1536, 768, 768, 0);

    // MLP: f1 (no relu) -> f2 (relu) -> f3
    k_sgemm<<<dim3(4, 16), blk, 0, stream>>>(hcat, 1536, f1w, 1024, 0, f1b, nullptr, nullptr, x1, 1024, 1024, 1536, 0);
    k_sgemm<<<dim3(2, 16), blk, 0, stream>>>(x1, 1024, f2w, 512, 0, f2b_, nullptr, nullptr, x2, 512, 512, 1024, 1);
    k_sgemm<<<dim3(4, 16), blk, 0, stream>>>(x2, 512, f3w, 1024, 0, f3b, nullptr, nullptr, out, 1024, 1024, 512, 0);
}

// Round 2
// 1905.993 us; speedup vs baseline: 1.3161x; 1.3161x over previous
//
#include <hip/hip_runtime.h>
#include <hip/hip_cooperative_groups.h>
#include <math.h>

namespace cg = cooperative_groups;

// B=64, T=32, D=768, NH=2, dk=384, N=901 (1 cls + 900 local)

typedef short bf16x8 __attribute__((ext_vector_type(8)));
typedef float f32x4 __attribute__((ext_vector_type(4)));
typedef unsigned short ushort_t;

#define GRU_NB 48

__device__ __forceinline__ unsigned short f2b(float f) {
    unsigned int u = __float_as_uint(f);
    unsigned int r = (u + 0x7FFFu + ((u >> 16) & 1u)) >> 16;
    return (unsigned short)r;
}
__device__ __forceinline__ float b2f(unsigned short s) {
    return __uint_as_float(((unsigned int)s) << 16);
}
__device__ __forceinline__ float sigm(float x) { return 1.f / (1.f + __expf(-x)); }
__device__ __forceinline__ float tanhx(float x) {
    x = fminf(fmaxf(x, -15.f), 15.f);
    float e = __expf(2.f * x);
    return (e - 1.f) / (e + 1.f);
}

// ---------------- setup: convert weights to bf16, pool sums, zero barrier ----------------

__global__ void k_cvt_all(const float* __restrict__ whh, const float* __restrict__ la0,
                          const float* __restrict__ la1, const float* __restrict__ h0,
                          const float* __restrict__ gp, const float* __restrict__ lp,
                          ushort_t* __restrict__ whhb, ushort_t* __restrict__ law0b,
                          ushort_t* __restrict__ law1b, ushort_t* __restrict__ h0b,
                          float* __restrict__ hbuf, float* __restrict__ scal,
                          int* __restrict__ bar) {
    if (blockIdx.x == 0) {
        int t = threadIdx.x;
        if (t < 64) {
            float v1 = (t < 32) ? gp[t] : 0.f;
            float v2 = (t < 32) ? lp[t] : 0.f;
#pragma unroll
            for (int m = 1; m < 32; m <<= 1) { v1 += __shfl_xor(v1, m, 64); v2 += __shfl_xor(v2, m, 64); }
            if (t == 0) { scal[0] = v1; scal[1] = v2; }
        } else if (t < 96) {
            bar[t - 64] = 0;
        }
    }
    long i = (long)blockIdx.x * 256 + threadIdx.x;
    const long n1 = 2304L * 768, n2 = n1 + 768L * 768, n3 = n2 + 768L * 768, n4 = n3 + 64L * 768;
    if (i < n1) whhb[i] = f2b(whh[i]);
    else if (i < n2) law0b[i - n1] = f2b(la0[i - n1]);
    else if (i < n3) law1b[i - n2] = f2b(la1[i - n2]);
    else if (i < n4) { float v = h0[i - n3]; h0b[i - n3] = f2b(v); hbuf[i - n3] = v; }
}

// ---------------- fp32 sgemm, 4 rows x 4 cols per thread, optional dual problem via z ----------------

struct SgP {
    const float* A; const float* B; const float* bias;
    const float* s1; const float* s2; float* C;
    long lda; int ldb, ldc, N, K, relu, transB;
};

__global__ void __launch_bounds__(256) k_sg(SgP pp0, SgP pp1) {
    SgP p = (blockIdx.z == 0) ? pp0 : pp1;
    __shared__ float As[4 * 1536];
    int m0 = blockIdx.y * 4;
    for (int r = 0; r < 4; r++)
        for (int k = threadIdx.x; k < p.K; k += 256)
            As[r * p.K + k] = p.A[(long)(m0 + r) * p.lda + k];
    __syncthreads();
    int n0 = (blockIdx.x * 256 + threadIdx.x) * 4;
    if (n0 >= p.N) return;
    float acc[4][4] = {};
    if (!p.transB) {
        for (int k = 0; k < p.K; k += 4) {
            float4 b0 = *(const float4*)(p.B + (long)(k + 0) * p.ldb + n0);
            float4 b1 = *(const float4*)(p.B + (long)(k + 1) * p.ldb + n0);
            float4 b2v = *(const float4*)(p.B + (long)(k + 2) * p.ldb + n0);
            float4 b3 = *(const float4*)(p.B + (long)(k + 3) * p.ldb + n0);
#pragma unroll
            for (int r = 0; r < 4; r++) {
                float4 a = *(const float4*)&As[r * p.K + k];
                acc[r][0] += a.x * b0.x + a.y * b1.x + a.z * b2v.x + a.w * b3.x;
                acc[r][1] += a.x * b0.y + a.y * b1.y + a.z * b2v.y + a.w * b3.y;
                acc[r][2] += a.x * b0.z + a.y * b1.z + a.z * b2v.z + a.w * b3.z;
                acc[r][3] += a.x * b0.w + a.y * b1.w + a.z * b2v.w + a.w * b3.w;
            }
        }
    } else {
        const float* B0 = p.B + (long)(n0 + 0) * p.ldb;
        const float* B1 = p.B + (long)(n0 + 1) * p.ldb;
        const float* B2 = p.B + (long)(n0 + 2) * p.ldb;
        const float* B3 = p.B + (long)(n0 + 3) * p.ldb;
        for (int k = 0; k < p.K; k += 4) {
            float4 t0 = *(const float4*)(B0 + k);
            float4 t1 = *(const float4*)(B1 + k);
            float4 t2 = *(const float4*)(B2 + k);
            float4 t3 = *(const float4*)(B3 + k);
#pragma unroll
            for (int r = 0; r < 4; r++) {
                float4 a = *(const float4*)&As[r * p.K + k];
                acc[r][0] += a.x * t0.x + a.y * t0.y + a.z * t0.z + a.w * t0.w;
                acc[r][1] += a.x * t1.x + a.y * t1.y + a.z * t1.z + a.w * t1.w;
                acc[r][2] += a.x * t2.x + a.y * t2.y + a.z * t2.z + a.w * t2.w;
                acc[r][3] += a.x * t3.x + a.y * t3.y + a.z * t3.z + a.w * t3.w;
            }
        }
    }
    float s1 = p.s1 ? *p.s1 : 1.f;
    float s2 = p.s2 ? *p.s2 : 1.f;
    float bv[4] = {0.f, 0.f, 0.f, 0.f};
    if (p.bias) {
        float4 b4 = *(const float4*)(p.bias + n0);
        bv[0] = b4.x * s2; bv[1] = b4.y * s2; bv[2] = b4.z * s2; bv[3] = b4.w * s2;
    }
#pragma unroll
    for (int r = 0; r < 4; r++) {
        float4 o;
        o.x = acc[r][0] * s1 + bv[0]; o.y = acc[r][1] * s1 + bv[1];
        o.z = acc[r][2] * s1 + bv[2]; o.w = acc[r][3] * s1 + bv[3];
        if (p.relu) { o.x = fmaxf(o.x, 0.f); o.y = fmaxf(o.y, 0.f); o.z = fmaxf(o.z, 0.f); o.w = fmaxf(o.w, 0.f); }
        *(float4*)(p.C + (long)(m0 + r) * p.ldc + n0) = o;
    }
}

// base[b][j] = wx[b][j] + b_ih[j] (+ b_hh[j] for r,z gates)
__global__ void k_base(const float* __restrict__ wx, const float* __restrict__ bih,
                       const float* __restrict__ bhh, float* __restrict__ base) {
    int i = blockIdx.x * 256 + threadIdx.x;
    if (i < 64 * 2304) {
        int j = i % 2304;
        float v = wx[i] + bih[j];
        if (j < 1536) v += bhh[j];
        base[i] = v;
    }
}

// ---------------- GRU scan: 48 blocks x 192 thr, whh/base/h resident in LDS, custom barrier ----------------

__global__ void __launch_bounds__(192) k_gru_coop(
    const ushort_t* __restrict__ h0b, const float* __restrict__ h0f,
    const ushort_t* __restrict__ whh, const float* __restrict__ base,
    const float* __restrict__ bhh, ushort_t* __restrict__ qemb, int* __restrict__ bar)
{
    __shared__ __align__(16) ushort_t whh_s[3][16][776];
    __shared__ float gs[3][64][20];
    __shared__ float bs[3][64][20];
    __shared__ float h_s[64][20];
    __shared__ float bhh_s[16];
    int tid = threadIdx.x;
    int g = tid >> 6, lane = tid & 63, quad = lane >> 4, l16 = lane & 15;
    int j = blockIdx.x, d0 = j * 16;
    // preload whh slice (wave g loads gate g's 16 rows)
    for (int r = 0; r < 16; r++)
        for (int kk = lane * 8; kk < 768; kk += 512)
            *(bf16x8*)&whh_s[g][r][kk] = *(const bf16x8*)&whh[(size_t)(g * 768 + d0 + r) * 768 + kk];
    // preload base slice and h slice
    for (int e = tid; e < 3072; e += 192) {
        int g2 = e >> 10, rem = e & 1023, b = rem >> 4, c = rem & 15;
        bs[g2][b][c] = base[b * 2304 + g2 * 768 + d0 + c];
    }
    for (int e = tid; e < 1024; e += 192) {
        int b = e >> 4, c = e & 15;
        h_s[b][c] = h0f[b * 768 + d0 + c];
    }
    if (tid < 16) bhh_s[tid] = bhh[1536 + d0 + tid];
    __syncthreads();
    for (int t = 0; t < 32; t++) {
        const ushort_t* Ap = (t == 0) ? h0b : (qemb + (size_t)(t - 1) * 768);
        size_t ldA = (t == 0) ? 768 : (size_t)32 * 768;
        f32x4 zz4 = {0.f, 0.f, 0.f, 0.f};
        f32x4 acc[4];
#pragma unroll
        for (int mi = 0; mi < 4; mi++) acc[mi] = zz4;
        for (int kk = 0; kk < 768; kk += 32) {
            bf16x8 bfr = *(const bf16x8*)&whh_s[g][l16][kk + quad * 8];
#pragma unroll
            for (int mi = 0; mi < 4; mi++) {
                bf16x8 af = *(const bf16x8*)(Ap + (size_t)(mi * 16 + l16) * ldA + kk + quad * 8);
                acc[mi] = __builtin_amdgcn_mfma_f32_16x16x32_bf16(af, bfr, acc[mi], 0, 0, 0);
            }
        }
#pragma unroll
        for (int mi = 0; mi < 4; mi++)
#pragma unroll
            for (int r = 0; r < 4; r++)
                gs[g][mi * 16 + quad * 4 + r][l16] = acc[mi][r];
        __syncthreads();
        for (int e = tid; e < 1024; e += 192) {
            int b = e >> 4, c = e & 15;
            float rr = sigm(gs[0][b][c] + bs[0][b][c]);
            float zg = sigm(gs[1][b][c] + bs[1][b][c]);
            float nn = tanhx(bs[2][b][c] + rr * (gs[2][b][c] + bhh_s[c]));
            float hv = h_s[b][c];
            float hnew = (1.f - zg) * nn + zg * hv;
            h_s[b][c] = hnew;
            qemb[((size_t)b * 32 + t) * 768 + d0 + c] = f2b(hnew);
        }
        __syncthreads();
        if (t < 31) {
            if (tid == 0) {
                __threadfence();                       // release: flush XCD L2 so qemb[t] is globally visible
                atomicAdd(&bar[t], 1);
                while (atomicAdd(&bar[t], 0) < GRU_NB) __builtin_amdgcn_s_sleep(2);
            }
            __syncthreads();
        }
    }
}

// fallback (non-coop): 32 per-step launches, 12 blocks x 256 (round-1 design)
__device__ __forceinline__ void gru_step_g(
    int t, const ushort_t* __restrict__ h0b, const ushort_t* __restrict__ whh,
    const float* __restrict__ base, float bhhn,
    float* __restrict__ h, ushort_t* __restrict__ qemb,
    int d0, int quad, int l16)
{
    const ushort_t* Ap = (t == 0) ? h0b : (qemb + (long)(t - 1) * 768);
    long ldA = (t == 0) ? 768 : 32 * 768;
    int d = d0 + l16;
    f32x4 zz4 = {0.f, 0.f, 0.f, 0.f};
    f32x4 acc[3][4];
#pragma unroll
    for (int g = 0; g < 3; g++)
#pragma unroll
        for (int mi = 0; mi < 4; mi++) acc[g][mi] = zz4;
    for (int kk = 0; kk < 768; kk += 32) {
        bf16x8 af[4];
#pragma unroll
        for (int mi = 0; mi < 4; mi++)
            af[mi] = *(const bf16x8*)(Ap + (long)(mi * 16 + l16) * ldA + kk + quad * 8);
#pragma unroll
        for (int g = 0; g < 3; g++) {
            bf16x8 bfr = *(const bf16x8*)(whh + (long)(g * 768 + d0 + l16) * 768 + kk + quad * 8);
#pragma unroll
            for (int mi = 0; mi < 4; mi++)
                acc[g][mi] = __builtin_amdgcn_mfma_f32_16x16x32_bf16(af[mi], bfr, acc[g][mi], 0, 0, 0);
        }
    }
#pragma unroll
    for (int mi = 0; mi < 4; mi++) {
#pragma unroll
        for (int r = 0; r < 4; r++) {
            int b = mi * 16 + quad * 4 + r;
            const float* bb = base + b * 2304;
            float rr = sigm(acc[0][mi][r] + bb[d]);
            float zg = sigm(acc[1][mi][r] + bb[768 + d]);
            float nn = tanhx(bb[1536 + d] + rr * (acc[2][mi][r] + bhhn));
            float hv = h[b * 768 + d];
            float hnew = (1.f - zg) * nn + zg * hv;
            h[b * 768 + d] = hnew;
            qemb[(long)(b * 32 + t) * 768 + d] = f2b(hnew);
        }
    }
}

__global__ void __launch_bounds__(256) k_gru_step(
    int t, const ushort_t* h0b, const ushort_t* whh, const float* base,
    const float* bhh, float* h, ushort_t* qemb)
{
    int wv = threadIdx.x >> 6, lane = threadIdx.x & 63;
    int quad = lane >> 4, l16 = lane & 15;
    int d0 = blockIdx.x * 64 + wv * 16;
    float bhhn = bhh[1536 + d0 + l16];
    gru_step_g(t, h0b, whh, base, bhhn, h, qemb, d0, quad, l16);
}

// ---------------- generic bf16 MFMA GEMM (64x64 tile) ----------------

__global__ void __launch_bounds__(256) k_gemm_bf16(
    const ushort_t* __restrict__ A, int lda,
    const ushort_t* __restrict__ B, int ldb, int transB,
    const float* __restrict__ bias,
    ushort_t* __restrict__ Cb, int ldc,
    int K, int remap, int rowoff)
{
    __shared__ __align__(16) ushort_t As[64][72];
    __shared__ __align__(16) ushort_t Bs[64][72];
    int tid = threadIdx.x;
    int wv = tid >> 6, lane = tid & 63, quad = lane >> 4, l16 = lane & 15;
    long bm = (long)blockIdx.y * 64, bn = (long)blockIdx.x * 64;
    f32x4 zz4 = {0.f, 0.f, 0.f, 0.f};
    f32x4 acc[4];
#pragma unroll
    for (int mi = 0; mi < 4; mi++) acc[mi] = zz4;
    int row4 = tid >> 2, seg = tid & 3;
    for (int k0 = 0; k0 < K; k0 += 64) {
        {
            const ushort_t* src = A + (bm + row4) * lda + k0 + seg * 16;
            *(bf16x8*)&As[row4][seg * 16] = *(const bf16x8*)src;
            *(bf16x8*)&As[row4][seg * 16 + 8] = *(const bf16x8*)(src + 8);
        }
        if (transB) {
            const ushort_t* src = B + (bn + row4) * ldb + k0 + seg * 16;
            *(bf16x8*)&Bs[row4][seg * 16] = *(const bf16x8*)src;
            *(bf16x8*)&Bs[row4][seg * 16 + 8] = *(const bf16x8*)(src + 8);
        } else {
            const ushort_t* src = B + (long)(k0 + row4) * ldb + bn + seg * 16;
            bf16x8 v0 = *(const bf16x8*)src;
            bf16x8 v1 = *(const bf16x8*)(src + 8);
#pragma unroll
            for (int i = 0; i < 8; i++) {
                Bs[seg * 16 + i][row4] = (ushort_t)v0[i];
                Bs[seg * 16 + 8 + i][row4] = (ushort_t)v1[i];
            }
        }
        __syncthreads();
#pragma unroll
        for (int ks = 0; ks < 64; ks += 32) {
            bf16x8 bfr = *(const bf16x8*)&Bs[wv * 16 + l16][ks + quad * 8];
#pragma unroll
            for (int mi = 0; mi < 4; mi++) {
                bf16x8 af = *(const bf16x8*)&As[mi * 16 + l16][ks + quad * 8];
                acc[mi] = __builtin_amdgcn_mfma_f32_16x16x32_bf16(af, bfr, acc[mi], 0, 0, 0);
            }
        }
        __syncthreads();
    }
    int ncol = (int)bn + wv * 16 + l16;
    float bv = bias ? bias[ncol] : 0.f;
#pragma unroll
    for (int mi = 0; mi < 4; mi++) {
#pragma unroll
        for (int r = 0; r < 4; r++) {
            long row = bm + mi * 16 + quad * 4 + r;
            long orow = remap ? ((row >> 5) * 64 + rowoff + (row & 31)) : row;
            Cb[orow * ldc + ncol] = f2b(acc[mi][r] + bv);
        }
    }
}

// qb[b*64 + h*32 + q] = Q_h[b,q,:] . la_b1_h
__global__ void k_qb(const ushort_t* __restrict__ Qb, const float* __restrict__ lb1,
                     float* __restrict__ qbv) {
    int i = blockIdx.x * 256 + threadIdx.x;
    if (i >= 4096) return;
    int b = i >> 6, r = i & 63, hh = r >> 5, q = r & 31;
    const ushort_t* src = Qb + (long)(b * 32 + q) * 768 + hh * 384;
    const float* bb = lb1 + hh * 384;
    float s = 0.f;
    for (int k = 0; k < 384; k++) s += b2f(src[k]) * bb[k];
    qbv[i] = s;
}

// ---------------- fused flash attention, key-split partials ----------------
// grid (b, split). Each split handles its tile range of the 29 key tiles; writes
// unnormalized acc (bf16) + running m,l.

__global__ void __launch_bounds__(512) k_flash(
    const float* __restrict__ img, const ushort_t* __restrict__ Qt,
    const float* __restrict__ qb, float* __restrict__ pm, float* __restrict__ pl,
    ushort_t* __restrict__ pacc, int nsplit)
{
    __shared__ __align__(16) ushort_t xs[32][776];
    __shared__ float Sls[64][36];
    __shared__ __align__(16) ushort_t Pls[64][40];
    __shared__ float m_s[64], l_s[64], al_s[64], qb_s[64];
    int b = blockIdx.x;
    int sp = blockIdx.y;
    int tper = (29 + nsplit - 1) / nsplit;
    int tb = sp * tper, te = min(29, tb + tper);
    int tid = threadIdx.x;
    int wv = tid >> 6, lane = tid & 63, quad = lane >> 4, l16 = lane & 15;
    if (tid < 64) { qb_s[tid] = qb[b * 64 + tid]; m_s[tid] = -1e30f; l_s[tid] = 0.f; }
    f32x4 zz4 = {0.f, 0.f, 0.f, 0.f};
    f32x4 acc[4][6];
#pragma unroll
    for (int mi = 0; mi < 4; mi++)
#pragma unroll
        for (int nj = 0; nj < 6; nj++) acc[mi][nj] = zz4;
    const float rs = 0.051031036307982884f; // 1/sqrt(384)
    int smi = wv & 3, sni = wv >> 2;
    __syncthreads();
    for (int t0 = tb; t0 < te; t0++) {
        int key0 = t0 * 32;
        { // stage x tile (fp32 global -> bf16 LDS), zero-fill past key 899
            int keyl = tid >> 4, dseg = tid & 15;
            int key = key0 + keyl;
            const float* src = img + ((long)b * 901 + 1 + key) * 768;
            bool ok = key < 900;
#pragma unroll
            for (int c = 0; c < 12; c++) {
                int dd = c * 64 + dseg * 4;
                float x0 = 0, x1 = 0, x2 = 0, x3 = 0;
                if (ok) { float4 v = *(const float4*)(src + dd); x0 = v.x; x1 = v.y; x2 = v.z; x3 = v.w; }
                ushort_t* dst = &xs[keyl][dd];
                dst[0] = f2b(x0); dst[1] = f2b(x1); dst[2] = f2b(x2); dst[3] = f2b(x3);
            }
        }
        __syncthreads();
        { // S = Qt @ x^T
            f32x4 as = zz4;
            const ushort_t* qrow = Qt + (long)(b * 64 + smi * 16 + l16) * 768 + quad * 8;
            const ushort_t* xrow = &xs[sni * 16 + l16][quad * 8];
#pragma unroll
            for (int kk = 0; kk < 768; kk += 32) {
                bf16x8 aq = *(const bf16x8*)(qrow + kk);
                bf16x8 bx = *(const bf16x8*)(xrow + kk);
                as = __builtin_amdgcn_mfma_f32_16x16x32_bf16(aq, bx, as, 0, 0, 0);
            }
#pragma unroll
            for (int r = 0; r < 4; r++) {
                int row = smi * 16 + quad * 4 + r;
                Sls[row][sni * 16 + l16] = (as[r] + qb_s[row]) * rs;
            }
        }
        __syncthreads();
        { // online softmax: 8 threads per row
            int row = tid >> 3, sub = tid & 7;
            float sv[4];
            float mx = -1e30f;
#pragma unroll
            for (int i = 0; i < 4; i++) {
                int kl = sub + i * 8;
                float s = (key0 + kl < 900) ? Sls[row][kl] : -1e30f;
                sv[i] = s; mx = fmaxf(mx, s);
            }
            mx = fmaxf(mx, __shfl_xor(mx, 1, 64));
            mx = fmaxf(mx, __shfl_xor(mx, 2, 64));
            mx = fmaxf(mx, __shfl_xor(mx, 4, 64));
            float mold = m_s[row];
            float mnew = fmaxf(mold, mx);
            float ss = 0.f;
#pragma unroll
            for (int i = 0; i < 4; i++) {
                float p = __expf(sv[i] - mnew);
                ss += p;
                Pls[row][sub + i * 8] = f2b(p);
            }
            ss += __shfl_xor(ss, 1, 64);
            ss += __shfl_xor(ss, 2, 64);
            ss += __shfl_xor(ss, 4, 64);
            if (sub == 0) {
                float alpha = __expf(mold - mnew);
                al_s[row] = alpha;
                l_s[row] = l_s[row] * alpha + ss;
                m_s[row] = mnew;
            }
        }
        __syncthreads();
        { // rescale + acc += P @ x
            bf16x8 pf[4];
#pragma unroll
            for (int mi = 0; mi < 4; mi++)
                pf[mi] = *(const bf16x8*)&Pls[mi * 16 + l16][quad * 8];
#pragma unroll
            for (int mi = 0; mi < 4; mi++) {
#pragma unroll
                for (int r = 0; r < 4; r++) {
                    float a = al_s[mi * 16 + quad * 4 + r];
#pragma unroll
                    for (int nj = 0; nj < 6; nj++) acc[mi][nj][r] *= a;
                }
            }
#pragma unroll
            for (int nj = 0; nj < 6; nj++) {
                int dd = wv * 96 + nj * 16 + l16;
                bf16x8 bx;
#pragma unroll
                for (int j = 0; j < 8; j++) bx[j] = (short)xs[quad * 8 + j][dd];
#pragma unroll
                for (int mi = 0; mi < 4; mi++)
                    acc[mi][nj] = __builtin_amdgcn_mfma_f32_16x16x32_bf16(pf[mi], bx, acc[mi][nj], 0, 0, 0);
            }
        }
        __syncthreads();
    }
    // write partials (unnormalized)
    if (tid < 64) {
        pm[(b * nsplit + sp) * 64 + tid] = m_s[tid];
        pl[(b * nsplit + sp) * 64 + tid] = l_s[tid];
    }
#pragma unroll
    for (int mi = 0; mi < 4; mi++) {
#pragma unroll
        for (int r = 0; r < 4; r++) {
            int row = mi * 16 + quad * 4 + r;
            ushort_t* dst = pacc + ((size_t)(b * nsplit + sp) * 64 + row) * 768;
#pragma unroll
            for (int nj = 0; nj < 6; nj++)
                dst[wv * 96 + nj * 16 + l16] = f2b(acc[mi][nj][r]);
        }
    }
}

// combine partials + pool over q:  plX[b][h][d] = sum_q lp[q] * ctx[b, h*32+q, d]
__global__ void __launch_bounds__(256) k_combine(
    const float* __restrict__ pm, const float* __restrict__ pl,
    const ushort_t* __restrict__ pacc, const float* __restrict__ lp,
    float* __restrict__ plX, int nsplit)
{
    __shared__ float wsh[4][64];
    __shared__ float lps[64];
    int b = blockIdx.y, tid = threadIdx.x;
    if (tid < 64) {
        float mmax = -1e30f;
        for (int s = 0; s < nsplit; s++) mmax = fmaxf(mmax, pm[(b * nsplit + s) * 64 + tid]);
        float lsum = 0.f;
        for (int s = 0; s < nsplit; s++)
            lsum += __expf(pm[(b * nsplit + s) * 64 + tid] - mmax) * pl[(b * nsplit + s) * 64 + tid];
        float inv = 1.f / lsum;
        for (int s = 0; s < nsplit; s++)
            wsh[s][tid] = __expf(pm[(b * nsplit + s) * 64 + tid] - mmax) * inv;
        lps[tid] = lp[tid & 31];
    }
    __syncthreads();
    int d = blockIdx.x * 256 + tid;
    float p0 = 0.f, p1 = 0.f;
    for (int row = 0; row < 64; row++) {
        float v = 0.f;
        for (int s = 0; s < nsplit; s++)
            v += wsh[s][row] * b2f(pacc[((size_t)(b * nsplit + s) * 64 + row) * 768 + d]);
        float wq = lps[row];
        if (row < 32) p0 += wq * v; else p1 += wq * v;
    }
    plX[b * 1536 + d] = p0;
    plX[b * 1536 + 768 + d] = p1;
}

// ---------------- host launcher ----------------

extern "C" void kernel_launch(void* const* d_in, const int* in_sizes, int n_in,
                              void* d_out, int out_size, void* d_ws, size_t ws_size,
                              hipStream_t stream)
{
    const float* img  = (const float*)d_in[1];
    const float* h0   = (const float*)d_in[2];
    const float* w_ih = (const float*)d_in[3];
    const float* w_hh = (const float*)d_in[4];
    const float* b_ih = (const float*)d_in[5];
    const float* b_hh = (const float*)d_in[6];
    const float* ga_w = (const float*)d_in[7];
    const float* ga_b = (const float*)d_in[8];
    const float* ga_pool = (const float*)d_in[9];
    const float* la_w = (const float*)d_in[10];
    const float* la_b = (const float*)d_in[11];
    const float* la_pool = (const float*)d_in[12];
    const float* go_w = (const float*)d_in[13];
    const float* go_b = (const float*)d_in[14];
    const float* go_pool = (const float*)d_in[15];
    const float* f1w = (const float*)d_in[16];
    const float* f1b = (const float*)d_in[17];
    const float* f2w = (const float*)d_in[18];
    const float* f2b_ = (const float*)d_in[19];
    const float* f3w = (const float*)d_in[20];
    const float* f3b = (const float*)d_in[21];
    float* out = (float*)d_out;
    (void)in_sizes; (void)n_in; (void)out_size;

    int nsplit = (ws_size >= (size_t)44 * 1024 * 1024) ? 4 : 2;

    char* w = (char*)d_ws;
    auto alloc = [&](size_t bytes) -> char* {
        char* p = w; w += (bytes + 255) & ~(size_t)255; return p;
    };
    // persistent region
    float*    scal  = (float*)alloc(256);                 // [0]=S_go [1]=S_la
    int*      bar   = (int*)alloc(256);
    ushort_t* law0b = (ushort_t*)alloc((size_t)768 * 768 * 2);
    ushort_t* law1b = (ushort_t*)alloc((size_t)768 * 768 * 2);
    ushort_t* h0b   = (ushort_t*)alloc((size_t)64 * 768 * 2);
    ushort_t* qembb = (ushort_t*)alloc((size_t)2048 * 768 * 2);
    ushort_t* Qb    = (ushort_t*)alloc((size_t)2048 * 768 * 2);
    ushort_t* Qtb   = (ushort_t*)alloc((size_t)4096 * 768 * 2);
    float*    qbv   = (float*)alloc((size_t)4096 * 4);
    float*    pm    = (float*)alloc((size_t)64 * 4 * 64 * 4);
    float*    pl    = (float*)alloc((size_t)64 * 4 * 64 * 4);
    float*    plX   = (float*)alloc((size_t)64 * 1536 * 4);
    float*    pc    = (float*)alloc((size_t)64 * 768 * 4);
    float*    hcat  = (float*)alloc((size_t)64 * 1536 * 4);
    float*    x1    = (float*)alloc((size_t)64 * 1024 * 4);
    float*    x2    = (float*)alloc((size_t)64 * 512 * 4);
    // union region: [GRU-phase temporaries] overlaid with [flash pacc]
    char* uni = w;
    char* u = uni;
    auto ualloc = [&](size_t bytes) -> char* {
        char* p = u; u += (bytes + 255) & ~(size_t)255; return p;
    };
    ushort_t* whhb  = (ushort_t*)ualloc((size_t)2304 * 768 * 2);
    float*    t12   = (float*)ualloc((size_t)2 * 64 * 768 * 4);
    float*    avec  = (float*)ualloc((size_t)64 * 768 * 4);
    float*    wx    = (float*)ualloc((size_t)64 * 2304 * 4);
    float*    base  = (float*)ualloc((size_t)64 * 2304 * 4);
    float*    hbuf  = (float*)ualloc((size_t)64 * 768 * 4);
    ushort_t* pacc  = (ushort_t*)uni;   // overlays GRU temporaries; used only after GRU完
    float*    t12g  = t12 + 64 * 768;

    const float* ga_w2 = ga_w + 2 * 768 * 768; const float* ga_w3 = ga_w + 3 * 768 * 768;
    const float* ga_b2 = ga_b + 2 * 768;       const float* ga_b3 = ga_b + 3 * 768;
    const float* go_w2 = go_w + 2 * 768 * 768; const float* go_w3 = go_w + 3 * 768 * 768;
    const float* go_b2 = go_b + 2 * 768;       const float* go_b3 = go_b + 3 * 768;
    const float* la_w0 = la_w;                 const float* la_w1 = la_w + 768 * 768;
    const float* la_w2 = la_w + 2 * 768 * 768; const float* la_w3 = la_w + 3 * 768 * 768;
    const float* la_b0 = la_b;                 const float* la_b1 = la_b + 768;
    const float* la_b2 = la_b + 2 * 768;       const float* la_b3 = la_b + 3 * 768;

    dim3 blk(256);
    // setup: bf16 conversions + pool sums + barrier zero
    k_cvt_all<<<11712, blk, 0, stream>>>(w_hh, la_w0, la_w1, h0, go_pool, la_pool,
                                         whhb, law0b, law1b, h0b, hbuf, scal, bar);

    auto mkp = [](const float* A, long lda, const float* B, int ldb, const float* bias,
                  const float* s1, const float* s2, float* C, int ldc, int N, int K,
                  int relu, int transB) {
        SgP p; p.A = A; p.B = B; p.bias = bias; p.s1 = s1; p.s2 = s2; p.C = C;
        p.lda = lda; p.ldb = ldb; p.ldc = ldc; p.N = N; p.K = K; p.relu = relu; p.transB = transB;
        return p;
    };

    // ga stage1 || go stage1 (shared A = img_cls)
    {
        SgP p0 = mkp(img, (long)901 * 768, ga_w2, 768, ga_b2, nullptr, nullptr, t12, 768, 768, 768, 0, 0);
        SgP p1 = mkp(img, (long)901 * 768, go_w2, 768, go_b2, nullptr, nullptr, t12g, 768, 768, 768, 0, 0);
        k_sg<<<dim3(1, 16, 2), blk, 0, stream>>>(p0, p1);
    }
    // ga stage2 || go stage2
    {
        SgP p0 = mkp(t12, 768, ga_w3, 768, ga_b3, ga_pool, ga_pool, avec, 768, 768, 768, 0, 0);
        SgP p1 = mkp(t12g, 768, go_w3, 768, go_b3, scal, scal, hcat + 768, 1536, 768, 768, 0, 0);
        k_sg<<<dim3(1, 16, 2), blk, 0, stream>>>(p0, p1);
    }
    // wx = avec @ w_ih^T
    {
        SgP p0 = mkp(avec, 768, w_ih, 768, nullptr, nullptr, nullptr, wx, 2304, 2304, 768, 0, 1);
        k_sg<<<dim3(3, 16, 1), blk, 0, stream>>>(p0, p0);
    }
    k_base<<<576, blk, 0, stream>>>(wx, b_ih, b_hh, base);

    // GRU scan
    {
        const ushort_t* a0 = h0b; const float* a1 = h0; const ushort_t* a2 = whhb;
        const float* a3 = base; const float* a4 = b_hh; ushort_t* a5 = qembb; int* a6 = bar;
        void* args[7] = { &a0, &a1, &a2, &a3, &a4, &a5, &a6 };
        hipError_t e = hipLaunchCooperativeKernel((void*)k_gru_coop, dim3(GRU_NB), dim3(192),
                                                  args, 0, stream);
        if (e != hipSuccess) {
            for (int t = 0; t < 32; t++)
                k_gru_step<<<12, blk, 0, stream>>>(t, h0b, whhb, base, b_hh, hbuf, qembb);
        }
    }

    // Q = q_emb @ la_w0 + la_b0 ; Qt_h = Q_h @ W1_h^T ; qb = Q_h . b1_h
    k_gemm_bf16<<<dim3(12, 32), blk, 0, stream>>>(qembb, 768, law0b, 768, 0, la_b0, Qb, 768, 768, 0, 0);
    k_gemm_bf16<<<dim3(12, 32), blk, 0, stream>>>(Qb, 768, law1b, 768, 1, nullptr, Qtb, 768, 384, 1, 0);
    k_gemm_bf16<<<dim3(12, 32), blk, 0, stream>>>(Qb + 384, 768, law1b + 384, 768, 1, nullptr, Qtb, 768, 384, 1, 32);
    k_qb<<<16, blk, 0, stream>>>(Qb, la_b1, qbv);

    // flash attention, key-split, then combine+pool
    k_flash<<<dim3(64, nsplit), dim3(512), 0, stream>>>(img, Qtb, qbv, pm, pl, pacc, nsplit);
    k_combine<<<dim3(3, 64), blk, 0, stream>>>(pm, pl, pacc, la_pool, plX, nsplit);

    // pc = pooledX_h @ W2_h + S_la*b2_h   (two heads batched via z)
    {
        SgP p0 = mkp(plX, 1536, la_w2, 768, la_b2, nullptr, scal + 1, pc, 768, 384, 768, 0, 0);
        SgP p1 = mkp(plX + 768, 1536, la_w2 + 384, 768, la_b2 + 384, nullptr, scal + 1, pc + 384, 768, 384, 768, 0, 0);
        k_sg<<<dim3(1, 16, 2), blk, 0, stream>>>(p0, p1);
    }
    // local_out = pc @ la_w3 + S_la*b3
    {
        SgP p0 = mkp(pc, 768, la_w3, 768, la_b3, nullptr, scal + 1, hcat, 1536, 768, 768, 0, 0);
        k_sg<<<dim3(1, 16, 1), blk, 0, stream>>>(p0, p0);
    }
    // MLP: f1 -> relu(f2) -> f3
    {
        SgP p0 = mkp(hcat, 1536, f1w, 1024, f1b, nullptr, nullptr, x1, 1024, 1024, 1536, 0, 0);
        k_sg<<<dim3(1, 16, 1), blk, 0, stream>>>(p0, p0);
    }
    {
        SgP p0 = mkp(x1, 1024, f2w, 512, f2b_, nullptr, nullptr, x2, 512, 512, 1024, 1, 0);
        k_sg<<<dim3(1, 16, 1), blk, 0, stream>>>(p0, p0);
    }
    {
        SgP p0 = mkp(x2, 512, f3w, 1024, f3b, nullptr, nullptr, out, 1024, 1024, 512, 0, 0);
        k_sg<<<dim3(1, 16, 1), blk, 0, stream>>>(p0, p0);
    }
}

// Round 3
// 1745.627 us; speedup vs baseline: 1.4370x; 1.0919x over previous
//
#include <hip/hip_runtime.h>
#include <math.h>

// B=64, T=32, D=768, NH=2, dk=384, N=901 (1 cls + 900 local)

typedef short bf16x8 __attribute__((ext_vector_type(8)));
typedef float f32x4 __attribute__((ext_vector_type(4)));
typedef unsigned short ushort_t;

#define GRU_NB 48

__device__ __forceinline__ unsigned short f2b(float f) {
    unsigned int u = __float_as_uint(f);
    unsigned int r = (u + 0x7FFFu + ((u >> 16) & 1u)) >> 16;
    return (unsigned short)r;
}
__device__ __forceinline__ float b2f(unsigned short s) {
    return __uint_as_float(((unsigned int)s) << 16);
}
__device__ __forceinline__ float sigm(float x) { return 1.f / (1.f + __expf(-x)); }
__device__ __forceinline__ float tanhx(float x) {
    x = fminf(fmaxf(x, -15.f), 15.f);
    float e = __expf(2.f * x);
    return (e - 1.f) / (e + 1.f);
}

// flag barrier: arrival = agent store of monotonically-increasing phase id; poll =
// parallel relaxed agent loads (no RMW contention). Data written before the barrier
// must use agent-scope stores (bypass L2 -> L3) so readers' plain loads (fresh lines)
// see it. flags zeroed by k_cvt_all each launch.
__device__ __forceinline__ void gbar(int* flags, int nb, int phase, int bid, int tid) {
    __syncthreads();   // drains each wave's vmcnt -> agent stores are in L3
    if (tid == 0) __hip_atomic_store(&flags[bid], phase, __ATOMIC_RELAXED, __HIP_MEMORY_SCOPE_AGENT);
    if (tid < 64) {
        for (;;) {
            int v = 0x7fffffff;
            for (int f = tid; f < nb; f += 64)
                v = min(v, __hip_atomic_load(&flags[f], __ATOMIC_RELAXED, __HIP_MEMORY_SCOPE_AGENT));
            if (__all(v >= phase)) break;
            __builtin_amdgcn_s_sleep(1);
        }
    }
    __syncthreads();
}

// ---------------- setup: convert weights to bf16, pool sums, zero flags ----------------

__global__ void k_cvt_all(const float* __restrict__ whh, const float* __restrict__ la0,
                          const float* __restrict__ la1, const float* __restrict__ h0,
                          const float* __restrict__ gp, const float* __restrict__ lp,
                          ushort_t* __restrict__ whhb, ushort_t* __restrict__ law0b,
                          ushort_t* __restrict__ law1b, ushort_t* __restrict__ h0b,
                          float* __restrict__ hbuf, float* __restrict__ scal,
                          int* __restrict__ bar) {
    if (blockIdx.x == 0) {
        int t = threadIdx.x;
        if (t < 64) {
            float v1 = (t < 32) ? gp[t] : 0.f;
            float v2 = (t < 32) ? lp[t] : 0.f;
#pragma unroll
            for (int m = 1; m < 32; m <<= 1) { v1 += __shfl_xor(v1, m, 64); v2 += __shfl_xor(v2, m, 64); }
            if (t == 0) { scal[0] = v1; scal[1] = v2; }
        }
        for (int i = threadIdx.x; i < 1024; i += 256) bar[i] = 0;
    }
    long i = (long)blockIdx.x * 256 + threadIdx.x;
    const long n1 = 2304L * 768, n2 = n1 + 768L * 768, n3 = n2 + 768L * 768, n4 = n3 + 64L * 768;
    if (i < n1) whhb[i] = f2b(whh[i]);
    else if (i < n2) law0b[i - n1] = f2b(la0[i - n1]);
    else if (i < n3) law1b[i - n2] = f2b(la1[i - n2]);
    else if (i < n4) { float v = h0[i - n3]; h0b[i - n3] = f2b(v); hbuf[i - n3] = v; }
}

// ---------------- generic fp32 tile GEMM: 4 rows x <=256 cols per block ----------------
// out = acc*s1 + bias[c]*s2 (+ bias2[c] if c<b2lim); optional relu; optional agent store.

__device__ __forceinline__ void tgemm(
    const float* __restrict__ A, long lda,
    const float* __restrict__ Bm, int ldb, int transB,
    const float* __restrict__ bias, float s1, float s2,
    const float* __restrict__ bias2, int b2lim,
    float* __restrict__ C, int ldc, int ncols, int K, int relu, int agent,
    int m0, int n0, float* As, int tid)
{
    for (int r = 0; r < 4; r++)
        for (int k = tid; k < K; k += 256)
            As[r * K + k] = A[(long)(m0 + r) * lda + k];
    __syncthreads();
    if (tid < ncols) {
        int c = n0 + tid;
        float a0 = 0, a1 = 0, a2 = 0, a3 = 0;
        if (!transB) {
            for (int k = 0; k < K; k += 4) {
                float b0 = Bm[(long)(k + 0) * ldb + c];
                float b1 = Bm[(long)(k + 1) * ldb + c];
                float b2v = Bm[(long)(k + 2) * ldb + c];
                float b3 = Bm[(long)(k + 3) * ldb + c];
                float4 x0 = *(const float4*)&As[0 * K + k];
                float4 x1 = *(const float4*)&As[1 * K + k];
                float4 x2 = *(const float4*)&As[2 * K + k];
                float4 x3 = *(const float4*)&As[3 * K + k];
                a0 += x0.x * b0 + x0.y * b1 + x0.z * b2v + x0.w * b3;
                a1 += x1.x * b0 + x1.y * b1 + x1.z * b2v + x1.w * b3;
                a2 += x2.x * b0 + x2.y * b1 + x2.z * b2v + x2.w * b3;
                a3 += x3.x * b0 + x3.y * b1 + x3.z * b2v + x3.w * b3;
            }
        } else {
            const float* Bp = Bm + (long)c * ldb;
            for (int k = 0; k < K; k += 4) {
                float4 bv = *(const float4*)(Bp + k);
                float4 x0 = *(const float4*)&As[0 * K + k];
                float4 x1 = *(const float4*)&As[1 * K + k];
                float4 x2 = *(const float4*)&As[2 * K + k];
                float4 x3 = *(const float4*)&As[3 * K + k];
                a0 += x0.x * bv.x + x0.y * bv.y + x0.z * bv.z + x0.w * bv.w;
                a1 += x1.x * bv.x + x1.y * bv.y + x1.z * bv.z + x1.w * bv.w;
                a2 += x2.x * bv.x + x2.y * bv.y + x2.z * bv.z + x2.w * bv.w;
                a3 += x3.x * bv.x + x3.y * bv.y + x3.z * bv.z + x3.w * bv.w;
            }
        }
        float bb = (bias ? bias[c] * s2 : 0.f) + ((bias2 && c < b2lim) ? bias2[c] : 0.f);
        float o0 = a0 * s1 + bb, o1 = a1 * s1 + bb, o2 = a2 * s1 + bb, o3 = a3 * s1 + bb;
        if (relu) { o0 = fmaxf(o0, 0.f); o1 = fmaxf(o1, 0.f); o2 = fmaxf(o2, 0.f); o3 = fmaxf(o3, 0.f); }
        if (agent) {
            __hip_atomic_store(&C[(long)(m0 + 0) * ldc + c], o0, __ATOMIC_RELAXED, __HIP_MEMORY_SCOPE_AGENT);
            __hip_atomic_store(&C[(long)(m0 + 1) * ldc + c], o1, __ATOMIC_RELAXED, __HIP_MEMORY_SCOPE_AGENT);
            __hip_atomic_store(&C[(long)(m0 + 2) * ldc + c], o2, __ATOMIC_RELAXED, __HIP_MEMORY_SCOPE_AGENT);
            __hip_atomic_store(&C[(long)(m0 + 3) * ldc + c], o3, __ATOMIC_RELAXED, __HIP_MEMORY_SCOPE_AGENT);
        } else {
            C[(long)(m0 + 0) * ldc + c] = o0;
            C[(long)(m0 + 1) * ldc + c] = o1;
            C[(long)(m0 + 2) * ldc + c] = o2;
            C[(long)(m0 + 3) * ldc + c] = o3;
        }
    }
}

// ---------------- fused head: t12/t12g -> avec/global_out -> base (3 phases) ----------------

struct HeadP {
    const float *img, *ga_w2, *ga_b2, *go_w2, *go_b2;
    const float *ga_w3, *ga_b3, *go_w3, *go_b3;
    const float *ga_pool, *scal, *w_ih, *b_ih, *b_hh;
    float *t12, *t12g, *avec, *hcat, *base;
    int* flags; int p0, p1;
};

__global__ void __launch_bounds__(256) k_head(HeadP P) {
    __shared__ float As[4 * 768];
    int bid = blockIdx.x, tid = threadIdx.x;
    for (int p = P.p0; p <= P.p1; p++) {
        if (p == 1) {
            if (bid < 96) {
                int prob = bid / 48, r = bid % 48, m4 = r / 3, nt = r % 3;
                tgemm(P.img, 901L * 768, prob ? P.go_w2 : P.ga_w2, 768, 0,
                      prob ? P.go_b2 : P.ga_b2, 1.f, 1.f, nullptr, 0,
                      prob ? P.t12g : P.t12, 768, 256, 768, 0, 1, m4 * 4, nt * 256, As, tid);
            }
        } else if (p == 2) {
            if (bid < 96) {
                int prob = bid / 48, r = bid % 48, m4 = r / 3, nt = r % 3;
                float sc = prob ? P.scal[0] : P.ga_pool[0];
                tgemm(prob ? P.t12g : P.t12, 768, prob ? P.go_w3 : P.ga_w3, 768, 0,
                      prob ? P.go_b3 : P.ga_b3, sc, sc, nullptr, 0,
                      prob ? (P.hcat + 768) : P.avec, prob ? 1536 : 768, 256, 768, 0, 1,
                      m4 * 4, nt * 256, As, tid);
            }
        } else if (p == 3) {
            if (bid < 144) {
                int m4 = bid / 9, nt = bid % 9;
                // base = avec @ w_ih^T + b_ih (+ b_hh for first 1536 cols)
                tgemm(P.avec, 768, P.w_ih, 768, 1, P.b_ih, 1.f, 1.f, P.b_hh, 1536,
                      P.base, 2304, 256, 768, 0, 0, m4 * 4, nt * 256, As, tid);
            }
        }
        if (p < P.p1) gbar(P.flags, 144, p, bid, tid);
    }
}

// ---------------- GRU scan: 48 blocks x 192 thr, whh/base/h in LDS, flag barrier ----------------

struct GruP {
    const ushort_t* h0b; const float* h0f; const ushort_t* whh;
    const float* base; const float* bhh; ushort_t* qemb; int* flags;
};

__global__ void __launch_bounds__(192) k_gru_coop(GruP P) {
    __shared__ __align__(16) ushort_t whh_s[3][16][776];
    __shared__ float gs[3][64][20];
    __shared__ float bs[3][64][20];
    __shared__ float h_s[64][20];
    __shared__ float bhh_s[16];
    int tid = threadIdx.x;
    int g = tid >> 6, lane = tid & 63, quad = lane >> 4, l16 = lane & 15;
    int j = blockIdx.x, d0 = j * 16;
    for (int r = 0; r < 16; r++)
        for (int kk = lane * 8; kk < 768; kk += 512)
            *(bf16x8*)&whh_s[g][r][kk] = *(const bf16x8*)&P.whh[(size_t)(g * 768 + d0 + r) * 768 + kk];
    for (int e = tid; e < 3072; e += 192) {
        int g2 = e >> 10, rem = e & 1023, b = rem >> 4, c = rem & 15;
        bs[g2][b][c] = P.base[b * 2304 + g2 * 768 + d0 + c];
    }
    for (int e = tid; e < 1024; e += 192) {
        int b = e >> 4, c = e & 15;
        h_s[b][c] = P.h0f[b * 768 + d0 + c];
    }
    if (tid < 16) bhh_s[tid] = P.bhh[1536 + d0 + tid];
    __syncthreads();
    for (int t = 0; t < 32; t++) {
        const ushort_t* Ap = (t == 0) ? P.h0b : (P.qemb + (size_t)(t - 1) * 768);
        size_t ldA = (t == 0) ? 768 : (size_t)32 * 768;
        f32x4 zz4 = {0.f, 0.f, 0.f, 0.f};
        f32x4 acc[4];
#pragma unroll
        for (int mi = 0; mi < 4; mi++) acc[mi] = zz4;
        for (int kk = 0; kk < 768; kk += 32) {
            bf16x8 bfr = *(const bf16x8*)&whh_s[g][l16][kk + quad * 8];
#pragma unroll
            for (int mi = 0; mi < 4; mi++) {
                bf16x8 af = *(const bf16x8*)(Ap + (size_t)(mi * 16 + l16) * ldA + kk + quad * 8);
                acc[mi] = __builtin_amdgcn_mfma_f32_16x16x32_bf16(af, bfr, acc[mi], 0, 0, 0);
            }
        }
#pragma unroll
        for (int mi = 0; mi < 4; mi++)
#pragma unroll
            for (int r = 0; r < 4; r++)
                gs[g][mi * 16 + quad * 4 + r][l16] = acc[mi][r];
        __syncthreads();
        for (int e = tid; e < 512; e += 192) {
            int b = e >> 3, c0 = (e & 7) * 2;
            float hn[2];
#pragma unroll
            for (int u = 0; u < 2; u++) {
                int c = c0 + u;
                float rr = sigm(gs[0][b][c] + bs[0][b][c]);
                float zg = sigm(gs[1][b][c] + bs[1][b][c]);
                float nn = tanhx(bs[2][b][c] + rr * (gs[2][b][c] + bhh_s[c]));
                float hv = h_s[b][c];
                hn[u] = (1.f - zg) * nn + zg * hv;
                h_s[b][c] = hn[u];
            }
            unsigned int pk = (unsigned int)f2b(hn[0]) | ((unsigned int)f2b(hn[1]) << 16);
            __hip_atomic_store((unsigned int*)&P.qemb[((size_t)b * 32 + t) * 768 + d0 + c0],
                               pk, __ATOMIC_RELAXED, __HIP_MEMORY_SCOPE_AGENT);
        }
        __syncthreads();   // drain agent stores to L3 before flag
        if (t < 31) {
            if (tid == 0)
                __hip_atomic_store(&P.flags[j], t + 1, __ATOMIC_RELAXED, __HIP_MEMORY_SCOPE_AGENT);
            if (tid < 64) {
                for (;;) {
                    int v = (tid < GRU_NB)
                        ? __hip_atomic_load(&P.flags[tid], __ATOMIC_RELAXED, __HIP_MEMORY_SCOPE_AGENT)
                        : 0x7fffffff;
                    if (__all(v > t)) break;
                    __builtin_amdgcn_s_sleep(1);
                }
            }
            __syncthreads();
        }
    }
}

// fallback (non-coop): 32 per-step launches
__global__ void __launch_bounds__(256) k_gru_step(
    int t, const ushort_t* h0b, const ushort_t* whh, const float* base,
    const float* bhh, float* h, ushort_t* qemb)
{
    int wv = threadIdx.x >> 6, lane = threadIdx.x & 63;
    int quad = lane >> 4, l16 = lane & 15;
    int d0 = blockIdx.x * 64 + wv * 16;
    float bhhn = bhh[1536 + d0 + l16];
    const ushort_t* Ap = (t == 0) ? h0b : (qemb + (long)(t - 1) * 768);
    long ldA = (t == 0) ? 768 : 32 * 768;
    int d = d0 + l16;
    f32x4 zz4 = {0.f, 0.f, 0.f, 0.f};
    f32x4 acc[3][4];
#pragma unroll
    for (int g = 0; g < 3; g++)
#pragma unroll
        for (int mi = 0; mi < 4; mi++) acc[g][mi] = zz4;
    for (int kk = 0; kk < 768; kk += 32) {
        bf16x8 af[4];
#pragma unroll
        for (int mi = 0; mi < 4; mi++)
            af[mi] = *(const bf16x8*)(Ap + (long)(mi * 16 + l16) * ldA + kk + quad * 8);
#pragma unroll
        for (int g = 0; g < 3; g++) {
            bf16x8 bfr = *(const bf16x8*)(whh + (long)(g * 768 + d0 + l16) * 768 + kk + quad * 8);
#pragma unroll
            for (int mi = 0; mi < 4; mi++)
                acc[g][mi] = __builtin_amdgcn_mfma_f32_16x16x32_bf16(af[mi], bfr, acc[g][mi], 0, 0, 0);
        }
    }
#pragma unroll
    for (int mi = 0; mi < 4; mi++) {
#pragma unroll
        for (int r = 0; r < 4; r++) {
            int b = mi * 16 + quad * 4 + r;
            const float* bb = base + b * 2304;
            float rr = sigm(acc[0][mi][r] + bb[d]);
            float zg = sigm(acc[1][mi][r] + bb[768 + d]);
            float nn = tanhx(bb[1536 + d] + rr * (acc[2][mi][r] + bhhn));
            float hv = h[b * 768 + d];
            float hnew = (1.f - zg) * nn + zg * hv;
            h[b * 768 + d] = hnew;
            qemb[(long)(b * 32 + t) * 768 + d] = f2b(hnew);
        }
    }
}

// ---------------- generic bf16 MFMA GEMM (64x64 tile) ----------------

__global__ void __launch_bounds__(256) k_gemm_bf16(
    const ushort_t* __restrict__ A, int lda,
    const ushort_t* __restrict__ B, int ldb, int transB,
    const float* __restrict__ bias,
    ushort_t* __restrict__ Cb, int ldc,
    int K, int remap, int rowoff)
{
    __shared__ __align__(16) ushort_t As[64][72];
    __shared__ __align__(16) ushort_t Bs[64][72];
    int tid = threadIdx.x;
    int wv = tid >> 6, lane = tid & 63, quad = lane >> 4, l16 = lane & 15;
    long bm = (long)blockIdx.y * 64, bn = (long)blockIdx.x * 64;
    f32x4 zz4 = {0.f, 0.f, 0.f, 0.f};
    f32x4 acc[4];
#pragma unroll
    for (int mi = 0; mi < 4; mi++) acc[mi] = zz4;
    int row4 = tid >> 2, seg = tid & 3;
    for (int k0 = 0; k0 < K; k0 += 64) {
        {
            const ushort_t* src = A + (bm + row4) * lda + k0 + seg * 16;
            *(bf16x8*)&As[row4][seg * 16] = *(const bf16x8*)src;
            *(bf16x8*)&As[row4][seg * 16 + 8] = *(const bf16x8*)(src + 8);
        }
        if (transB) {
            const ushort_t* src = B + (bn + row4) * ldb + k0 + seg * 16;
            *(bf16x8*)&Bs[row4][seg * 16] = *(const bf16x8*)src;
            *(bf16x8*)&Bs[row4][seg * 16 + 8] = *(const bf16x8*)(src + 8);
        } else {
            const ushort_t* src = B + (long)(k0 + row4) * ldb + bn + seg * 16;
            bf16x8 v0 = *(const bf16x8*)src;
            bf16x8 v1 = *(const bf16x8*)(src + 8);
#pragma unroll
            for (int i = 0; i < 8; i++) {
                Bs[seg * 16 + i][row4] = (ushort_t)v0[i];
                Bs[seg * 16 + 8 + i][row4] = (ushort_t)v1[i];
            }
        }
        __syncthreads();
#pragma unroll
        for (int ks = 0; ks < 64; ks += 32) {
            bf16x8 bfr = *(const bf16x8*)&Bs[wv * 16 + l16][ks + quad * 8];
#pragma unroll
            for (int mi = 0; mi < 4; mi++) {
                bf16x8 af = *(const bf16x8*)&As[mi * 16 + l16][ks + quad * 8];
                acc[mi] = __builtin_amdgcn_mfma_f32_16x16x32_bf16(af, bfr, acc[mi], 0, 0, 0);
            }
        }
        __syncthreads();
    }
    int ncol = (int)bn + wv * 16 + l16;
    float bv = bias ? bias[ncol] : 0.f;
#pragma unroll
    for (int mi = 0; mi < 4; mi++) {
#pragma unroll
        for (int r = 0; r < 4; r++) {
            long row = bm + mi * 16 + quad * 4 + r;
            long orow = remap ? ((row >> 5) * 64 + rowoff + (row & 31)) : row;
            Cb[orow * ldc + ncol] = f2b(acc[mi][r] + bv);
        }
    }
}

// ---------------- fused flash attention, key-split partials (qb folded in) ----------------

__global__ void __launch_bounds__(512) k_flash(
    const float* __restrict__ img, const ushort_t* __restrict__ Qt,
    const ushort_t* __restrict__ Qb, const float* __restrict__ la_b1,
    float* __restrict__ pm, float* __restrict__ pl,
    ushort_t* __restrict__ pacc, int nsplit)
{
    __shared__ __align__(16) ushort_t xs[32][776];
    __shared__ float Sls[64][36];
    __shared__ __align__(16) ushort_t Pls[64][40];
    __shared__ float m_s[64], l_s[64], al_s[64], qb_s[64];
    int b = blockIdx.x;
    int sp = blockIdx.y;
    int tper = (29 + nsplit - 1) / nsplit;
    int tb = sp * tper, te = min(29, tb + tper);
    int tid = threadIdx.x;
    int wv = tid >> 6, lane = tid & 63, quad = lane >> 4, l16 = lane & 15;
    { // qb_s[row] = Q_h[b,q,:] . la_b1_h   (8 lanes per row)
        int row = tid >> 3, sub = tid & 7;
        int hh = row >> 5, q = row & 31;
        const ushort_t* src = Qb + ((size_t)(b * 32 + q)) * 768 + hh * 384 + sub * 48;
        const float* bb = la_b1 + hh * 384 + sub * 48;
        float s = 0.f;
#pragma unroll
        for (int k = 0; k < 48; k++) s += b2f(src[k]) * bb[k];
        s += __shfl_xor(s, 1, 64); s += __shfl_xor(s, 2, 64); s += __shfl_xor(s, 4, 64);
        if (sub == 0) qb_s[row] = s;
    }
    if (tid < 64) { m_s[tid] = -1e30f; l_s[tid] = 0.f; }
    f32x4 zz4 = {0.f, 0.f, 0.f, 0.f};
    f32x4 acc[4][6];
#pragma unroll
    for (int mi = 0; mi < 4; mi++)
#pragma unroll
        for (int nj = 0; nj < 6; nj++) acc[mi][nj] = zz4;
    const float rs = 0.051031036307982884f; // 1/sqrt(384)
    int smi = wv & 3, sni = wv >> 2;
    __syncthreads();
    for (int t0 = tb; t0 < te; t0++) {
        int key0 = t0 * 32;
        { // stage x tile (fp32 global -> bf16 LDS), zero-fill past key 899
            int keyl = tid >> 4, dseg = tid & 15;
            int key = key0 + keyl;
            const float* src = img + ((long)b * 901 + 1 + key) * 768;
            bool ok = key < 900;
#pragma unroll
            for (int c = 0; c < 12; c++) {
                int dd = c * 64 + dseg * 4;
                float x0 = 0, x1 = 0, x2 = 0, x3 = 0;
                if (ok) { float4 v = *(const float4*)(src + dd); x0 = v.x; x1 = v.y; x2 = v.z; x3 = v.w; }
                ushort_t* dst = &xs[keyl][dd];
                dst[0] = f2b(x0); dst[1] = f2b(x1); dst[2] = f2b(x2); dst[3] = f2b(x3);
            }
        }
        __syncthreads();
        { // S = Qt @ x^T
            f32x4 as = zz4;
            const ushort_t* qrow = Qt + (long)(b * 64 + smi * 16 + l16) * 768 + quad * 8;
            const ushort_t* xrow = &xs[sni * 16 + l16][quad * 8];
#pragma unroll
            for (int kk = 0; kk < 768; kk += 32) {
                bf16x8 aq = *(const bf16x8*)(qrow + kk);
                bf16x8 bx = *(const bf16x8*)(xrow + kk);
                as = __builtin_amdgcn_mfma_f32_16x16x32_bf16(aq, bx, as, 0, 0, 0);
            }
#pragma unroll
            for (int r = 0; r < 4; r++) {
                int row = smi * 16 + quad * 4 + r;
                Sls[row][sni * 16 + l16] = (as[r] + qb_s[row]) * rs;
            }
        }
        __syncthreads();
        { // online softmax: 8 threads per row
            int row = tid >> 3, sub = tid & 7;
            float sv[4];
            float mx = -1e30f;
#pragma unroll
            for (int i = 0; i < 4; i++) {
                int kl = sub + i * 8;
                float s = (key0 + kl < 900) ? Sls[row][kl] : -1e30f;
                sv[i] = s; mx = fmaxf(mx, s);
            }
            mx = fmaxf(mx, __shfl_xor(mx, 1, 64));
            mx = fmaxf(mx, __shfl_xor(mx, 2, 64));
            mx = fmaxf(mx, __shfl_xor(mx, 4, 64));
            float mold = m_s[row];
            float mnew = fmaxf(mold, mx);
            float ss = 0.f;
#pragma unroll
            for (int i = 0; i < 4; i++) {
                float p = __expf(sv[i] - mnew);
                ss += p;
                Pls[row][sub + i * 8] = f2b(p);
            }
            ss += __shfl_xor(ss, 1, 64);
            ss += __shfl_xor(ss, 2, 64);
            ss += __shfl_xor(ss, 4, 64);
            if (sub == 0) {
                float alpha = __expf(mold - mnew);
                al_s[row] = alpha;
                l_s[row] = l_s[row] * alpha + ss;
                m_s[row] = mnew;
            }
        }
        __syncthreads();
        { // rescale + acc += P @ x
            bf16x8 pf[4];
#pragma unroll
            for (int mi = 0; mi < 4; mi++)
                pf[mi] = *(const bf16x8*)&Pls[mi * 16 + l16][quad * 8];
#pragma unroll
            for (int mi = 0; mi < 4; mi++) {
#pragma unroll
                for (int r = 0; r < 4; r++) {
                    float a = al_s[mi * 16 + quad * 4 + r];
#pragma unroll
                    for (int nj = 0; nj < 6; nj++) acc[mi][nj][r] *= a;
                }
            }
#pragma unroll
            for (int nj = 0; nj < 6; nj++) {
                int dd = wv * 96 + nj * 16 + l16;
                bf16x8 bx;
#pragma unroll
                for (int j = 0; j < 8; j++) bx[j] = (short)xs[quad * 8 + j][dd];
#pragma unroll
                for (int mi = 0; mi < 4; mi++)
                    acc[mi][nj] = __builtin_amdgcn_mfma_f32_16x16x32_bf16(pf[mi], bx, acc[mi][nj], 0, 0, 0);
            }
        }
        __syncthreads();
    }
    if (tid < 64) {
        pm[(b * nsplit + sp) * 64 + tid] = m_s[tid];
        pl[(b * nsplit + sp) * 64 + tid] = l_s[tid];
    }
#pragma unroll
    for (int mi = 0; mi < 4; mi++) {
#pragma unroll
        for (int r = 0; r < 4; r++) {
            int row = mi * 16 + quad * 4 + r;
            ushort_t* dst = pacc + ((size_t)(b * nsplit + sp) * 64 + row) * 768;
#pragma unroll
            for (int nj = 0; nj < 6; nj++)
                dst[wv * 96 + nj * 16 + l16] = f2b(acc[mi][nj][r]);
        }
    }
}

// ---------------- fused tail: combine+pool -> pc -> local_out -> f1 -> f2 -> f3 ----------------

struct TailP {
    const float *pm, *pl; const ushort_t* pacc; const float* lp;
    const float *la_w2, *la_b2, *la_w3, *la_b3, *scal;
    float *plX, *pc, *hcat;
    const float *f1w, *f1b, *f2w, *f2b, *f3w, *f3b;
    float *x1, *x2, *out;
    int* flags; int p0, p1, nsplit;
};

__global__ void __launch_bounds__(256) k_tail(TailP P) {
    __shared__ float As[4 * 1536];
    __shared__ float wsh[4][32];
    __shared__ float lpq[32];
    int bid = blockIdx.x, tid = threadIdx.x;
    float sla = P.scal[1];
    for (int p = P.p0; p <= P.p1; p++) {
        if (p == 0) {
            int b = bid >> 1, half = bid & 1, ns = P.nsplit;
            if (tid < 32) {
                int row = half * 32 + tid;
                float mmax = -1e30f;
                for (int s = 0; s < ns; s++) mmax = fmaxf(mmax, P.pm[(b * ns + s) * 64 + row]);
                float lsum = 0.f;
                for (int s = 0; s < ns; s++)
                    lsum += __expf(P.pm[(b * ns + s) * 64 + row] - mmax) * P.pl[(b * ns + s) * 64 + row];
                float inv = 1.f / lsum;
                for (int s = 0; s < ns; s++)
                    wsh[s][tid] = __expf(P.pm[(b * ns + s) * 64 + row] - mmax) * inv;
                lpq[tid] = P.lp[tid];
            }
            __syncthreads();
            for (int jj = 0; jj < 3; jj++) {
                int dd = tid + jj * 256;
                float accv = 0.f;
                for (int q = 0; q < 32; q++) {
                    float v = 0.f;
                    for (int s = 0; s < ns; s++)
                        v += wsh[s][q] * b2f(P.pacc[(((size_t)(b * ns + s)) * 64 + half * 32 + q) * 768 + dd]);
                    accv += lpq[q] * v;
                }
                __hip_atomic_store(&P.plX[b * 1536 + half * 768 + dd], accv,
                                   __ATOMIC_RELAXED, __HIP_MEMORY_SCOPE_AGENT);
            }
        } else if (p == 1) {
            if (bid < 64) {
                int prob = bid >> 5, r = bid & 31, m4 = r >> 1, nt = r & 1;
                tgemm(P.plX + prob * 768, 1536, P.la_w2 + prob * 384, 768, 0,
                      P.la_b2 + prob * 384, 1.f, sla, nullptr, 0,
                      P.pc + prob * 384, 768, nt ? 128 : 256, 768, 0, 1, m4 * 4, nt * 256, As, tid);
            }
        } else if (p == 2) {
            if (bid < 48) {
                int m4 = bid / 3, nt = bid % 3;
                tgemm(P.pc, 768, P.la_w3, 768, 0, P.la_b3, 1.f, sla, nullptr, 0,
                      P.hcat, 1536, 256, 768, 0, 1, m4 * 4, nt * 256, As, tid);
            }
        } else if (p == 3) {
            if (bid < 64) {
                int m4 = bid >> 2, nt = bid & 3;
                tgemm(P.hcat, 1536, P.f1w, 1024, 0, P.f1b, 1.f, 1.f, nullptr, 0,
                      P.x1, 1024, 256, 1536, 0, 1, m4 * 4, nt * 256, As, tid);
            }
        } else if (p == 4) {
            if (bid < 32) {
                int m4 = bid >> 1, nt = bid & 1;
                tgemm(P.x1, 1024, P.f2w, 512, 0, P.f2b, 1.f, 1.f, nullptr, 0,
                      P.x2, 512, 256, 1024, 1, 1, m4 * 4, nt * 256, As, tid);
            }
        } else if (p == 5) {
            if (bid < 64) {
                int m4 = bid >> 2, nt = bid & 3;
                tgemm(P.x2, 512, P.f3w, 1024, 0, P.f3b, 1.f, 1.f, nullptr, 0,
                      P.out, 1024, 256, 512, 0, 0, m4 * 4, nt * 256, As, tid);
            }
        }
        if (p < P.p1) gbar(P.flags, 128, p + 1, bid, tid);
    }
}

// ---------------- host launcher ----------------

extern "C" void kernel_launch(void* const* d_in, const int* in_sizes, int n_in,
                              void* d_out, int out_size, void* d_ws, size_t ws_size,
                              hipStream_t stream)
{
    const float* img  = (const float*)d_in[1];
    const float* h0   = (const float*)d_in[2];
    const float* w_ih = (const float*)d_in[3];
    const float* w_hh = (const float*)d_in[4];
    const float* b_ih = (const float*)d_in[5];
    const float* b_hh = (const float*)d_in[6];
    const float* ga_w = (const float*)d_in[7];
    const float* ga_b = (const float*)d_in[8];
    const float* ga_pool = (const float*)d_in[9];
    const float* la_w = (const float*)d_in[10];
    const float* la_b = (const float*)d_in[11];
    const float* la_pool = (const float*)d_in[12];
    const float* go_w = (const float*)d_in[13];
    const float* go_b = (const float*)d_in[14];
    const float* go_pool = (const float*)d_in[15];
    const float* f1w = (const float*)d_in[16];
    const float* f1b = (const float*)d_in[17];
    const float* f2w = (const float*)d_in[18];
    const float* f2b_ = (const float*)d_in[19];
    const float* f3w = (const float*)d_in[20];
    const float* f3b = (const float*)d_in[21];
    float* out = (float*)d_out;
    (void)in_sizes; (void)n_in; (void)out_size;

    int nsplit = (ws_size >= (size_t)43 * 1024 * 1024) ? 4 : 2;

    char* w = (char*)d_ws;
    auto alloc = [&](size_t bytes) -> char* {
        char* p = w; w += (bytes + 255) & ~(size_t)255; return p;
    };
    // persistent region
    float*    scal  = (float*)alloc(256);                 // [0]=S_go [1]=S_la
    int*      bar   = (int*)alloc(4096);                  // [0..63]=GRU [64..319]=head [320..447]=tail
    ushort_t* law0b = (ushort_t*)alloc((size_t)768 * 768 * 2);
    ushort_t* law1b = (ushort_t*)alloc((size_t)768 * 768 * 2);
    ushort_t* h0b   = (ushort_t*)alloc((size_t)64 * 768 * 2);
    ushort_t* qembb = (ushort_t*)alloc((size_t)2048 * 768 * 2);
    ushort_t* Qb    = (ushort_t*)alloc((size_t)2048 * 768 * 2);
    ushort_t* Qtb   = (ushort_t*)alloc((size_t)4096 * 768 * 2);
    float*    pm    = (float*)alloc((size_t)64 * 4 * 64 * 4);
    float*    pl    = (float*)alloc((size_t)64 * 4 * 64 * 4);
    float*    plX   = (float*)alloc((size_t)64 * 1536 * 4);
    float*    pc    = (float*)alloc((size_t)64 * 768 * 4);
    float*    hcat  = (float*)alloc((size_t)64 * 1536 * 4);
    float*    x1    = (float*)alloc((size_t)64 * 1024 * 4);
    float*    x2    = (float*)alloc((size_t)64 * 512 * 4);
    // union region: [GRU-phase temporaries] overlaid with [flash pacc]
    char* uni = w;
    char* u = uni;
    auto ualloc = [&](size_t bytes) -> char* {
        char* p = u; u += (bytes + 255) & ~(size_t)255; return p;
    };
    ushort_t* whhb  = (ushort_t*)ualloc((size_t)2304 * 768 * 2);
    float*    t12   = (float*)ualloc((size_t)2 * 64 * 768 * 4);
    float*    avec  = (float*)ualloc((size_t)64 * 768 * 4);
    float*    base  = (float*)ualloc((size_t)64 * 2304 * 4);
    float*    hbuf  = (float*)ualloc((size_t)64 * 768 * 4);
    ushort_t* pacc  = (ushort_t*)uni;   // overlays GRU temporaries; used only after GRU done
    float*    t12g  = t12 + 64 * 768;

    const float* ga_w2 = ga_w + 2 * 768 * 768; const float* ga_w3 = ga_w + 3 * 768 * 768;
    const float* ga_b2 = ga_b + 2 * 768;       const float* ga_b3 = ga_b + 3 * 768;
    const float* go_w2 = go_w + 2 * 768 * 768; const float* go_w3 = go_w + 3 * 768 * 768;
    const float* go_b2 = go_b + 2 * 768;       const float* go_b3 = go_b + 3 * 768;
    const float* la_w0 = la_w;                 const float* la_w1 = la_w + 768 * 768;
    const float* la_w2 = la_w + 2 * 768 * 768; const float* la_w3 = la_w + 3 * 768 * 768;
    const float* la_b0 = la_b;                 const float* la_b1 = la_b + 768;
    const float* la_b2 = la_b + 2 * 768;       const float* la_b3 = la_b + 3 * 768;

    dim3 blk(256);
    k_cvt_all<<<11712, blk, 0, stream>>>(w_hh, la_w0, la_w1, h0, go_pool, la_pool,
                                         whhb, law0b, law1b, h0b, hbuf, scal, bar);

    // fused head (coop; fallback: per-phase launches)
    {
        HeadP P;
        P.img = img; P.ga_w2 = ga_w2; P.ga_b2 = ga_b2; P.go_w2 = go_w2; P.go_b2 = go_b2;
        P.ga_w3 = ga_w3; P.ga_b3 = ga_b3; P.go_w3 = go_w3; P.go_b3 = go_b3;
        P.ga_pool = ga_pool; P.scal = scal; P.w_ih = w_ih; P.b_ih = b_ih; P.b_hh = b_hh;
        P.t12 = t12; P.t12g = t12g; P.avec = avec; P.hcat = hcat; P.base = base;
        P.flags = bar + 64; P.p0 = 1; P.p1 = 3;
        void* args[1] = { &P };
        hipError_t e = hipLaunchCooperativeKernel((void*)k_head, dim3(144), blk, args, 0, stream);
        if (e != hipSuccess)
            for (int p = 1; p <= 3; p++) { P.p0 = P.p1 = p; k_head<<<144, blk, 0, stream>>>(P); }
    }

    // GRU scan (coop; fallback: 32 step launches)
    {
        GruP P;
        P.h0b = h0b; P.h0f = h0; P.whh = whhb; P.base = base; P.bhh = b_hh;
        P.qemb = qembb; P.flags = bar;
        void* args[1] = { &P };
        hipError_t e = hipLaunchCooperativeKernel((void*)k_gru_coop, dim3(GRU_NB), dim3(192),
                                                  args, 0, stream);
        if (e != hipSuccess)
            for (int t = 0; t < 32; t++)
                k_gru_step<<<12, blk, 0, stream>>>(t, h0b, whhb, base, b_hh, hbuf, qembb);
    }

    // Q = q_emb @ la_w0 + la_b0 ; Qt_h = Q_h @ W1_h^T (folded-K trick)
    k_gemm_bf16<<<dim3(12, 32), blk, 0, stream>>>(qembb, 768, law0b, 768, 0, la_b0, Qb, 768, 768, 0, 0);
    k_gemm_bf16<<<dim3(12, 32), blk, 0, stream>>>(Qb, 768, law1b, 768, 1, nullptr, Qtb, 768, 384, 1, 0);
    k_gemm_bf16<<<dim3(12, 32), blk, 0, stream>>>(Qb + 384, 768, law1b + 384, 768, 1, nullptr, Qtb, 768, 384, 1, 32);

    // flash attention, key-split
    k_flash<<<dim3(64, nsplit), dim3(512), 0, stream>>>(img, Qtb, Qb, la_b1, pm, pl, pacc, nsplit);

    // fused tail (coop; fallback: per-phase launches)
    {
        TailP P;
        P.pm = pm; P.pl = pl; P.pacc = pacc; P.lp = la_pool;
        P.la_w2 = la_w2; P.la_b2 = la_b2; P.la_w3 = la_w3; P.la_b3 = la_b3; P.scal = scal;
        P.plX = plX; P.pc = pc; P.hcat = hcat;
        P.f1w = f1w; P.f1b = f1b; P.f2w = f2w; P.f2b = f2b_; P.f3w = f3w; P.f3b = f3b;
        P.x1 = x1; P.x2 = x2; P.out = out;
        P.flags = bar + 320; P.p0 = 0; P.p1 = 5; P.nsplit = nsplit;
        void* args[1] = { &P };
        hipError_t e = hipLaunchCooperativeKernel((void*)k_tail, dim3(128), blk, args, 0, stream);
        if (e != hipSuccess)
            for (int p = 0; p <= 5; p++) { P.p0 = P.p1 = p; k_tail<<<128, blk, 0, stream>>>(P); }
    }
}